// Round 14
// baseline (704.971 us; speedup 1.0000x reference)
//
#include <hip/hip_runtime.h>
#include <hip/hip_bf16.h>
#include <math.h>

#define NTN 60000
#define NCN 30000
#define NED 200000
// H=8, D=32, HID=256, FIN=64

typedef unsigned short u16;
typedef unsigned long long u64;
typedef __attribute__((ext_vector_type(8))) u16 u16x8;
typedef __attribute__((ext_vector_type(8))) __bf16 bf16x8;
typedef __attribute__((ext_vector_type(4))) float f32x4;

static __device__ __forceinline__ float bf2f(u16 u) {
    return __uint_as_float(((unsigned)u) << 16);
}
static __device__ __forceinline__ u16 f2bf(float f) {
    unsigned u = __float_as_uint(f);
    unsigned r = (u + 0x7fffu + ((u >> 16) & 1u)) >> 16;  // RNE
    return (u16)r;
}

// ------------------------- fill -------------------------
__global__ void fill2(unsigned* __restrict__ a, int na, unsigned* __restrict__ b, int nb) {
    int i = blockIdx.x * blockDim.x + threadIdx.x;
    int st = gridDim.x * blockDim.x;
    for (int k = i; k < na; k += st) a[k] = 0u;
    for (int k = i; k < nb; k += st) b[k] = 0u;
}

// ------------------------- conversions -------------------------
__global__ void f32_to_bf16_2(const float* __restrict__ in0, u16* __restrict__ out0, int n40,
                              const float* __restrict__ in1, u16* __restrict__ out1, int n41) {
    int i = blockIdx.x * blockDim.x + threadIdx.x;
    int stride = gridDim.x * blockDim.x;
    for (int k = i; k < n40; k += stride) {
        float4 v = ((const float4*)in0)[k];
        ushort4 o;
        o.x = f2bf(v.x); o.y = f2bf(v.y); o.z = f2bf(v.z); o.w = f2bf(v.w);
        ((ushort4*)out0)[k] = o;
    }
    for (int k = i; k < n41; k += stride) {
        float4 v = ((const float4*)in1)[k];
        ushort4 o;
        o.x = f2bf(v.x); o.y = f2bf(v.y); o.z = f2bf(v.z); o.w = f2bf(v.w);
        ((ushort4*)out1)[k] = o;
    }
}

// batched: out[m][n][k] = bf16(in[m][k][n]) with per-matrix strides.
__global__ void convTb(const float* __restrict__ in, u16* __restrict__ out,
                       int K, int N, int inStride, int outStride, int nm) {
    int idx = blockIdx.x * blockDim.x + threadIdx.x;
    int per = N * (K >> 2);
    int total = per * nm;
    if (idx >= total) return;
    int mat = idx / per, rem = idx - mat * per;
    int k4 = rem / N, n = rem - k4 * N;
    int k = k4 * 4;
    const float* src = in + (size_t)mat * inStride;
    u16* dst = out + (size_t)mat * outStride;
    ushort4 o;
    o.x = f2bf(src[(size_t)(k + 0) * N + n]);
    o.y = f2bf(src[(size_t)(k + 1) * N + n]);
    o.z = f2bf(src[(size_t)(k + 2) * N + n]);
    o.w = f2bf(src[(size_t)(k + 3) * N + n]);
    *(ushort4*)(dst + (size_t)n * K + k) = o;
}

// 4 groups of 256x256 (nm=4 each) transposes in one launch; blockIdx.y picks group.
__global__ void convT4(const float* __restrict__ s0, u16* __restrict__ d0, int is0, int os0,
                       const float* __restrict__ s1, u16* __restrict__ d1, int is1, int os1,
                       const float* __restrict__ s2, u16* __restrict__ d2, int is2, int os2,
                       const float* __restrict__ s3, u16* __restrict__ d3, int is3, int os3) {
    const float* in; u16* out; int inStride, outStride;
    switch (blockIdx.y) {
        case 0: in = s0; out = d0; inStride = is0; outStride = os0; break;
        case 1: in = s1; out = d1; inStride = is1; outStride = os1; break;
        case 2: in = s2; out = d2; inStride = is2; outStride = os2; break;
        default: in = s3; out = d3; inStride = is3; outStride = os3; break;
    }
    int idx = blockIdx.x * blockDim.x + threadIdx.x;
    const int per = 256 * 64;            // N * K/4
    int mat = idx / per, rem = idx - mat * per;
    int k4 = rem >> 8, n = rem & 255;
    int k = k4 * 4;
    const float* src = in + (size_t)mat * inStride;
    u16* dst = out + (size_t)mat * outStride;
    ushort4 o;
    o.x = f2bf(src[(size_t)(k + 0) * 256 + n]);
    o.y = f2bf(src[(size_t)(k + 1) * 256 + n]);
    o.z = f2bf(src[(size_t)(k + 2) * 256 + n]);
    o.w = f2bf(src[(size_t)(k + 3) * 256 + n]);
    *(ushort4*)(dst + (size_t)n * 256 + k) = o;
}

__global__ void copy_bq(const float* __restrict__ bq, float* __restrict__ bqkv) {
    int lt = blockIdx.x;
    bqkv[lt * 768 + threadIdx.x] = bq[lt * 256 + threadIdx.x];
}

// --------------------- weight fusion (all 4 lt in one launch) ---------------------
__global__ __launch_bounds__(256) void fuse_weights(
    const float* __restrict__ Wk, const float* __restrict__ bk,
    const float* __restrict__ Wv, const float* __restrict__ bv,
    const float* __restrict__ a_rel, const float* __restrict__ m_rel,
    const float* __restrict__ p_rel,
    float* __restrict__ Wf2, float* __restrict__ bqkv)
{
    __shared__ float kw[256], vw[256];
    const int c = blockIdx.x, lt = blockIdx.y, tid = threadIdx.x;
    const int l = lt >> 1, t = lt & 1;
    const int lr = l * 2 + (t == 1 ? 0 : 1);     // relation where type t is the SOURCE
    const float* WkP = Wk + (size_t)lt * 65536;
    const float* WvP = Wv + (size_t)lt * 65536;
    const float* ar = a_rel + (size_t)lr * 8192;
    const float* mr = m_rel + (size_t)lr * 8192;
    kw[tid] = WkP[c * 256 + tid];
    vw[tid] = WvP[c * 256 + tid];
    __syncthreads();
    const int h = tid >> 5, e = tid & 31;
    const float s = p_rel[lr * 8 + h] * 0.17677669529663687f;  // 1/sqrt(32)
    float ak = 0.f, av = 0.f;
#pragma unroll 8
    for (int d = 0; d < 32; ++d) {
        ak += kw[h * 32 + d] * ar[h * 1024 + d * 32 + e];
        av += vw[h * 32 + d] * mr[h * 1024 + d * 32 + e];
    }
    float* WkfP = Wf2 + (size_t)lt * 131072;
    WkfP[c * 256 + tid] = ak * s;
    WkfP[65536 + c * 256 + tid] = av;
    if (c == 0) {
        const float* bkP = bk + (size_t)lt * 256;
        const float* bvP = bv + (size_t)lt * 256;
        float bka = 0.f, bva = 0.f;
#pragma unroll 8
        for (int d = 0; d < 32; ++d) {
            bka += bkP[h * 32 + d] * ar[h * 1024 + d * 32 + e];
            bva += bvP[h * 32 + d] * mr[h * 1024 + d * 32 + e];
        }
        bqkv[lt * 768 + 256 + tid] = bka * s;
        bqkv[lt * 768 + 512 + tid] = bva;
    }
}

// ------------- MFMA GEMM: barrier-free wave-private pipelines (pair-merged) -------------
// Block = 4 waves; block tile 128 x 64; wave w owns rows [w*32, w*32+32) — NO data
// sharing between waves, ZERO s_barrier. A staged into wave-private dual-buffered
// LDS (4KB/buf) via global_load_lds; B (L2-resident weights) loaded straight to
// VGPRs (register double-buffer). Per-wave counted vmcnt(12) (4 A + 8 B loads/tile).
// Epilogue: wave-private LDS re-staging for coalesced bf16 row writes (same-wave
// DS ordering is in-order; no sync needed).
template <int EPI, bool OBF, int KT>
__global__ __launch_bounds__(256) void gemm_wp(
    int nblk0,
    const u16* __restrict__ A0, const u16* __restrict__ W0, const float* __restrict__ b0,
    void* __restrict__ C0, int M0, int ldC0, int NY0,
    const u16* __restrict__ xr0, const float* __restrict__ sk0,
    const u16* __restrict__ A1, const u16* __restrict__ W1, const float* __restrict__ b1,
    void* __restrict__ C1, int M1, int ldC1, int NY1,
    const u16* __restrict__ xr1, const float* __restrict__ sk1)
{
    constexpr int NT = KT >> 6;
    __shared__ u16 smem[16384];   // 4 waves x 2 bufs x 2048 u16 = 32 KB

    // bijective XCD swizzle (m204) over the merged grid
    const int nwg = gridDim.x;
    const int bid = blockIdx.x;
    const int q8 = nwg >> 3, r8 = nwg & 7;
    const int xcd = bid & 7, pos = bid >> 3;
    const int lbid = (xcd < r8) ? xcd * (q8 + 1) + pos
                                : r8 * (q8 + 1) + (xcd - r8) * q8 + pos;

    const u16* A; const u16* WT; const float* bias; void* Cv;
    int M, ldC, NY, sb; const u16* xres; const float* skipPtr;
    if (lbid < nblk0) {
        A = A0; WT = W0; bias = b0; Cv = C0; M = M0; ldC = ldC0; NY = NY0;
        xres = xr0; skipPtr = sk0; sb = lbid;
    } else {
        A = A1; WT = W1; bias = b1; Cv = C1; M = M1; ldC = ldC1; NY = NY1;
        xres = xr1; skipPtr = sk1; sb = lbid - nblk0;
    }
    const int bx = sb / NY, by = sb - bx * NY;
    const int tid = threadIdx.x;
    const int wave = tid >> 6, lane = tid & 63;
    const int m0 = bx * 128 + wave * 32;   // this wave's 32 rows
    const int n0 = by * 64;

    u16* Ab0 = smem + wave * 4096;
    u16* Ab1 = Ab0 + 2048;

    const int sr = lane >> 3;
    const int sl = lane & 7;

    // A: 4 x 8-row staging groups (wave-private rows)
    const u16* gpa[4];
#pragma unroll
    for (int i = 0; i < 4; ++i) {
        int gr = m0 + i * 8 + sr; gr = gr < M ? gr : M - 1;
        gpa[i] = A + (size_t)gr * KT + ((sl ^ sr) << 3);
    }
    // B: per-nf per-lane base (fragment read straight from row-major WT)
    const u16* gpb[4];
#pragma unroll
    for (int i = 0; i < 4; ++i)
        gpb[i] = WT + (size_t)(n0 + i * 16 + (lane & 15)) * KT + ((lane >> 4) << 3);

    f32x4 acc[2][4];
#pragma unroll
    for (int i = 0; i < 2; ++i)
#pragma unroll
        for (int j = 0; j < 4; ++j) acc[i][j] = (f32x4){0.f, 0.f, 0.f, 0.f};

    u16x8 Breg[2][4][2];

    auto stageA = [&](int t, u16* dst) {
#pragma unroll
        for (int i = 0; i < 4; ++i)
            __builtin_amdgcn_global_load_lds(
                (const __attribute__((address_space(1))) void*)(gpa[i] + t * 64),
                (__attribute__((address_space(3))) void*)(dst + i * 512), 16, 0, 0);
    };
    auto loadB = [&](int t, int s) {
#pragma unroll
        for (int nf = 0; nf < 4; ++nf)
#pragma unroll
            for (int kx = 0; kx < 2; ++kx)
                Breg[s][nf][kx] = *(const u16x8*)(gpb[nf] + t * 64 + kx * 32);
    };

    stageA(0, Ab0); loadB(0, 0);
    if constexpr (NT >= 2) { stageA(1, Ab1); loadB(1, 1); }

#pragma unroll
    for (int t = 0; t < NT; ++t) {
        const int pb = t & 1;
        if (t + 1 < NT) asm volatile("s_waitcnt vmcnt(12)" ::: "memory");
        else            asm volatile("s_waitcnt vmcnt(0)" ::: "memory");
        __builtin_amdgcn_sched_barrier(0);
        const u16* Ab = pb ? Ab1 : Ab0;
        bf16x8 af[2][2];
#pragma unroll
        for (int mf = 0; mf < 2; ++mf)
#pragma unroll
            for (int kx = 0; kx < 2; ++kx) {
                int r = mf * 16 + (lane & 15);
                int slot = (lane >> 4) + kx * 4;
                af[mf][kx] = __builtin_bit_cast(bf16x8,
                    *(const u16x8*)(Ab + r * 64 + ((slot ^ (r & 7)) << 3)));
            }
        asm volatile("s_waitcnt lgkmcnt(0)" ::: "memory");   // af in regs -> buf reusable
        __builtin_amdgcn_sched_barrier(0);
        if (t + 2 < NT) stageA(t + 2, pb ? Ab1 : Ab0);
#pragma unroll
        for (int kx = 0; kx < 2; ++kx)
#pragma unroll
            for (int mf = 0; mf < 2; ++mf)
#pragma unroll
                for (int nf = 0; nf < 4; ++nf)
                    acc[mf][nf] = __builtin_amdgcn_mfma_f32_16x16x32_bf16(
                        af[mf][kx], __builtin_bit_cast(bf16x8, Breg[pb][nf][kx]),
                        acc[mf][nf], 0, 0, 0);
        if (t + 2 < NT) loadB(t + 2, pb);   // after MFMAs read Breg[pb] (WAR respected)
    }

    float beta = 0.f;
    if (EPI == 2) beta = 1.f / (1.f + expf(-skipPtr[0]));

    if constexpr (OBF) {
        constexpr int CLD = 68;
        u16* Ct = smem + wave * 4096;   // wave-private; 32*68 = 2176 u16 < 4096
#pragma unroll
        for (int nf = 0; nf < 4; ++nf) {
            int col = nf * 16 + (lane & 15);
            int gcol = n0 + col;
            float bs = bias[gcol];
#pragma unroll
            for (int mf = 0; mf < 2; ++mf) {
#pragma unroll
                for (int j = 0; j < 4; ++j) {
                    int row = mf * 16 + (lane >> 4) * 4 + j;
                    int grow = m0 + row;
                    int gr2 = grow < M ? grow : 0;
                    float c = acc[mf][nf][j] + bs;
                    if (EPI == 1) c = fmaxf(c, 0.f);
                    if (EPI == 2) c = beta * c + (1.f - beta) * bf2f(xres[(size_t)gr2 * ldC + gcol]);
                    if (EPI == 3) c = (c > 0.f) ? c : 0.2f * c;
                    Ct[row * CLD + col] = f2bf(c);
                }
            }
        }
        // same-wave DS ordering: writes retire before reads below (in-order LDS pipe)
        int row = lane >> 1, c0 = (lane & 1) * 32;
        int grow = m0 + row;
        if (grow < M) {
            u16* dst = (u16*)Cv + (size_t)grow * ldC + n0 + c0;
            const u16* src = Ct + row * CLD + c0;
#pragma unroll
            for (int i = 0; i < 4; ++i)
                *(u16x8*)(dst + i * 8) = *(const u16x8*)(src + i * 8);
        }
    } else {
#pragma unroll
        for (int nf = 0; nf < 4; ++nf) {
            int gcol = n0 + nf * 16 + (lane & 15);
            float bs = bias[gcol];
#pragma unroll
            for (int mf = 0; mf < 2; ++mf) {
#pragma unroll
                for (int j = 0; j < 4; ++j) {
                    int grow = m0 + mf * 16 + (lane >> 4) * 4 + j;
                    if (grow >= M) continue;
                    float c = acc[mf][nf][j] + bs;
                    if (EPI == 1) c = fmaxf(c, 0.f);
                    if (EPI == 3) c = (c > 0.f) ? c : 0.2f * c;
                    ((float*)Cv)[(size_t)grow * ldC + gcol] = c;
                }
            }
        }
    }
}

// ------------------------- CSR build (both relations per launch) -------------------------
__global__ void hist2(const int* __restrict__ d0, unsigned* __restrict__ c0,
                      const int* __restrict__ d1, unsigned* __restrict__ c1, int E) {
    int e = blockIdx.x * blockDim.x + threadIdx.x;
    if (e < E) {
        atomicAdd(&c0[d0[e]], 1u);
        atomicAdd(&c1[d1[e]], 1u);
    }
}

__global__ __launch_bounds__(256) void scan_blocks2(
    const unsigned* __restrict__ c0, unsigned* __restrict__ p0, unsigned* __restrict__ bs0, int N0,
    const unsigned* __restrict__ c1, unsigned* __restrict__ p1, unsigned* __restrict__ bs1, int N1)
{
    const unsigned* counts = blockIdx.y ? c1 : c0;
    unsigned* pref = blockIdx.y ? p1 : p0;
    unsigned* bsum = blockIdx.y ? bs1 : bs0;
    int N = blockIdx.y ? N1 : N0;
    if ((int)blockIdx.x * 256 >= N) return;   // block-uniform early-out
    __shared__ unsigned tmp[256];
    int i = blockIdx.x * 256 + threadIdx.x;
    unsigned v = (i < N) ? counts[i] : 0u;
    tmp[threadIdx.x] = v;
    __syncthreads();
    for (int off = 1; off < 256; off <<= 1) {
        unsigned t = (threadIdx.x >= off) ? tmp[threadIdx.x - off] : 0u;
        __syncthreads();
        tmp[threadIdx.x] += t;
        __syncthreads();
    }
    if (i < N) pref[i] = tmp[threadIdx.x] - v;  // exclusive
    if (threadIdx.x == 255) bsum[blockIdx.x] = tmp[255];
}

__global__ __launch_bounds__(256) void scan_top2(
    unsigned* __restrict__ bs0, int NB0, unsigned* __restrict__ bs1, int NB1)
{
    unsigned* bsum = blockIdx.x ? bs1 : bs0;
    int NB = blockIdx.x ? NB1 : NB0;
    __shared__ unsigned tmp[256];
    unsigned v = ((int)threadIdx.x < NB) ? bsum[threadIdx.x] : 0u;
    tmp[threadIdx.x] = v;
    __syncthreads();
    for (int off = 1; off < 256; off <<= 1) {
        unsigned t = (threadIdx.x >= off) ? tmp[threadIdx.x - off] : 0u;
        __syncthreads();
        tmp[threadIdx.x] += t;
        __syncthreads();
    }
    if ((int)threadIdx.x < NB) bsum[threadIdx.x] = tmp[threadIdx.x] - v;  // exclusive
}

// packs rowstart|deg into one u64 per node (single load in edge kernel)
__global__ void scan_add2(
    const unsigned* __restrict__ p0, const unsigned* __restrict__ bs0,
    const unsigned* __restrict__ c0, unsigned* __restrict__ cur0, u64* __restrict__ ri0, int N0,
    const unsigned* __restrict__ p1, const unsigned* __restrict__ bs1,
    const unsigned* __restrict__ c1, unsigned* __restrict__ cur1, u64* __restrict__ ri1, int N1)
{
    const unsigned* pref = blockIdx.y ? p1 : p0;
    const unsigned* bsum = blockIdx.y ? bs1 : bs0;
    const unsigned* counts = blockIdx.y ? c1 : c0;
    unsigned* cursor = blockIdx.y ? cur1 : cur0;
    u64* rowinfo = blockIdx.y ? ri1 : ri0;
    int N = blockIdx.y ? N1 : N0;
    int i = blockIdx.x * 256 + threadIdx.x;
    if (i < N) {
        unsigned s = pref[i] + bsum[blockIdx.x];
        cursor[i] = s;
        rowinfo[i] = (u64)s | ((u64)counts[i] << 32);
    }
}

// stores PRE-MULTIPLIED row offset (src*768, u16 units).
__global__ void place2(const int* __restrict__ d0, const int* __restrict__ s0,
                       unsigned* __restrict__ cur0, unsigned* __restrict__ o0,
                       const int* __restrict__ d1, const int* __restrict__ s1,
                       unsigned* __restrict__ cur1, unsigned* __restrict__ o1, int E) {
    int e = blockIdx.x * blockDim.x + threadIdx.x;
    if (e < E) {
        unsigned p = atomicAdd(&cur0[d0[e]], 1u);
        o0[p] = (unsigned)s0[e] * 768u;
        unsigned q = atomicAdd(&cur1[d1[e]], 1u);
        o1[q] = (unsigned)s1[e] * 768u;
    }
}

// ------------------------- fused edge gather (2 nodes per wave) -------------------------
// Each 32-lane HALF owns ONE dst node (32 lanes x 16B = full 256-wide row):
// no cross-half merge; q-prep/softmax-finish/gelu/store serve 2 nodes per
// wave instruction. Online softmax w/ defer-max ballot fast path.
#define TBLK8 ((NTN + 7) / 8)
__global__ __launch_bounds__(256) void edge_gather2(
    const u16* __restrict__ qkvT, const u16* __restrict__ qkvC,
    const u64* __restrict__ riT, const unsigned* __restrict__ srcT,
    const u64* __restrict__ riC, const unsigned* __restrict__ srcC,
    u16* __restrict__ aggT, u16* __restrict__ aggC)
{
    const int b = blockIdx.x;
    const bool isT = b < TBLK8;
    const int lane = threadIdx.x & 63;
    const int lq = lane & 31;
    const int n = (((isT ? b : b - TBLK8) << 2) + (int)(threadIdx.x >> 6)) * 2 + (lane >> 5);

    const u16* qkv_d = isT ? qkvT : qkvC;
    const u16* qkv_s = isT ? qkvC : qkvT;
    const u64* ri = isT ? riT : riC;
    const unsigned* srcarr = isT ? srcT : srcC;
    u16* agg = isT ? aggT : aggC;

    const u64 rinfo = ri[n];
    const unsigned start = (unsigned)rinfo;
    const unsigned deg = (unsigned)(rinfo >> 32);
    u16* outp = &agg[(size_t)n * 256 + lq * 8];

    if (deg == 0) {
        *(u16x8*)outp = (u16x8){0, 0, 0, 0, 0, 0, 0, 0};
        return;
    }

    u16x8 qv = *(const u16x8*)&qkv_d[(size_t)n * 768 + lq * 8];
    float qf[8];
#pragma unroll
    for (int i = 0; i < 8; ++i) qf[i] = bf2f(qv[i]);

    const u16* kvb = qkv_s + 256 + lq * 8;   // k section base (lane folded); v at +256
    float m = -INFINITY, s = 0.f;
    float acc[8] = {0.f, 0.f, 0.f, 0.f, 0.f, 0.f, 0.f, 0.f};

    unsigned off = srcarr[start];
    u16x8 kr = *(const u16x8*)(kvb + off);
    u16x8 vr = *(const u16x8*)(kvb + off + 256);
    for (unsigned j = 0;;) {
        const bool more = (j + 1 < deg);
        u16x8 kr_n, vr_n;
        if (more) {
            unsigned off2 = srcarr[start + j + 1];
            kr_n = *(const u16x8*)(kvb + off2);
            vr_n = *(const u16x8*)(kvb + off2 + 256);
        }
        float kf[8];
#pragma unroll
        for (int i = 0; i < 8; ++i) kf[i] = bf2f(kr[i]);
        float p = qf[0] * kf[0] + qf[1] * kf[1] + qf[2] * kf[2] + qf[3] * kf[3]
                + qf[4] * kf[4] + qf[5] * kf[5] + qf[6] * kf[6] + qf[7] * kf[7];
        p += __shfl_xor(p, 1);
        p += __shfl_xor(p, 2);          // quad = the 4 lanes of this head (within half)
        float vf[8];
#pragma unroll
        for (int i = 0; i < 8; ++i) vf[i] = bf2f(vr[i]);
        if (__ballot(p > m) == 0ull) {
            float wv = __expf(p - m);
            s += wv;
#pragma unroll
            for (int i = 0; i < 8; ++i) acc[i] += wv * vf[i];
        } else {
            float mn = fmaxf(m, p);
            float sc = __expf(m - mn);  // 0 on first iteration (m = -inf)
            float wv = __expf(p - mn);
            s = s * sc + wv;
#pragma unroll
            for (int i = 0; i < 8; ++i) acc[i] = acc[i] * sc + wv * vf[i];
            m = mn;
        }
        if (!more) break;
        kr = kr_n; vr = vr_n; ++j;
    }

    float inv = 1.f / (s + 1e-16f);
    u16x8 ov;
#pragma unroll
    for (int i = 0; i < 8; ++i) {
        float x = acc[i] * inv;
        // gelu(x) ~= 0.5x(1+tanh(0.79788456(x+0.044715x^3))), tanh via expf
        float y2 = 1.5957691216f * x + 0.0713548163f * x * x * x;  // 2*y
        float e = __expf(y2);
        float t = 1.f - 2.f / (e + 1.f);
        ov[i] = f2bf(0.5f * x * (1.f + t));
    }
    *(u16x8*)outp = ov;
}

// ------------------------- misc -------------------------
__global__ __launch_bounds__(256) void norm_rows(float* __restrict__ y, int M) {
    int row = blockIdx.x * 4 + (threadIdx.x >> 6);
    int lane = threadIdx.x & 63;
    if (row >= M) return;
    float v = y[(size_t)row * 64 + lane];
    float s = v * v;
#pragma unroll
    for (int off = 1; off < 64; off <<= 1) s += __shfl_xor(s, off);
    float n = sqrtf(s);
    y[(size_t)row * 64 + lane] = v / fmaxf(n, 1e-12f);
}

// ------------------------- launch -------------------------
extern "C" void kernel_launch(void* const* d_in, const int* in_sizes, int n_in,
                              void* d_out, int out_size, void* d_ws, size_t ws_size,
                              hipStream_t stream)
{
    const float* x_trans = (const float*)d_in[0];
    const float* x_cc    = (const float*)d_in[1];
    const int* src_c2t   = (const int*)d_in[2];
    const int* dst_c2t   = (const int*)d_in[3];
    const int* src_t2c   = (const int*)d_in[4];
    const int* dst_t2c   = (const int*)d_in[5];
    const float* W_in = (const float*)d_in[6];
    const float* b_in = (const float*)d_in[7];
    const float* Wk   = (const float*)d_in[8];
    const float* bk   = (const float*)d_in[9];
    const float* Wq   = (const float*)d_in[10];
    const float* bq   = (const float*)d_in[11];
    const float* Wv   = (const float*)d_in[12];
    const float* bv   = (const float*)d_in[13];
    const float* Wa   = (const float*)d_in[14];
    const float* ba   = (const float*)d_in[15];
    const float* a_rel = (const float*)d_in[16];
    const float* m_rel = (const float*)d_in[17];
    const float* p_rel = (const float*)d_in[18];
    const float* skip  = (const float*)d_in[19];
    const float* W_out = (const float*)d_in[20];
    const float* b_out = (const float*)d_in[21];

    // ---------- workspace layout (~251 MB) ----------
    char* w = (char*)d_ws;
    auto alloc = [&](size_t bytes) { char* p = w; w += (bytes + 255) & ~(size_t)255; return p; };
    u16* xs0  = (u16*)alloc((size_t)NTN * 256 * 2);
    u16* xs1  = (u16*)alloc((size_t)NCN * 256 * 2);
    u16* xin0 = (u16*)alloc((size_t)NTN * 64 * 2);
    u16* xin1 = (u16*)alloc((size_t)NCN * 64 * 2);
    u16* qkv0 = (u16*)alloc((size_t)NTN * 768 * 2);   // 92.2 MB
    u16* qkv1 = (u16*)alloc((size_t)NCN * 768 * 2);   // 46.1 MB
    u16* agg0 = (u16*)alloc((size_t)NTN * 256 * 2);
    u16* agg1 = (u16*)alloc((size_t)NCN * 256 * 2);
    u16* WinT = (u16*)alloc((size_t)2 * 16384 * 2);
    u16* WqkvT= (u16*)alloc((size_t)4 * 196608 * 2);  // [768][256] per lt
    u16* WaT  = (u16*)alloc((size_t)4 * 65536 * 2);
    u16* WoutT= (u16*)alloc((size_t)16384 * 2);
    float* Wf2 = (float*)alloc((size_t)4 * 131072 * 4); // [lt][kf|vf] f32 staging
    float* bqkv = (float*)alloc((size_t)4 * 768 * 4);
    unsigned* countsT   = (unsigned*)alloc((size_t)NTN * 4);
    unsigned* prefT     = (unsigned*)alloc((size_t)NTN * 4);
    unsigned* cursorT   = (unsigned*)alloc((size_t)NTN * 4);
    u64* rowinfoT       = (u64*)alloc((size_t)NTN * 8);
    unsigned* srcAT     = (unsigned*)alloc((size_t)NED * 4);
    unsigned* countsC   = (unsigned*)alloc((size_t)NCN * 4);
    unsigned* prefC     = (unsigned*)alloc((size_t)NCN * 4);
    unsigned* cursorC   = (unsigned*)alloc((size_t)NCN * 4);
    u64* rowinfoC       = (u64*)alloc((size_t)NCN * 8);
    unsigned* srcAC     = (unsigned*)alloc((size_t)NED * 4);
    unsigned* bsum      = (unsigned*)alloc((size_t)2 * 256 * 4);
    (void)ws_size; (void)in_sizes; (void)n_in; (void)out_size;

    // ---------- CSR builds (both relations per launch; shared by both layers) ----------
    {
        const int EB = (NED + 255) / 256;
        const int NBt = (NTN + 255) / 256, NBc = (NCN + 255) / 256;
        fill2<<<256, 256, 0, stream>>>(countsT, NTN, countsC, NCN);
        hist2<<<EB, 256, 0, stream>>>(dst_c2t, countsT, dst_t2c, countsC, NED);
        scan_blocks2<<<dim3(NBt, 2), 256, 0, stream>>>(countsT, prefT, bsum, NTN,
                                                       countsC, prefC, bsum + 256, NCN);
        scan_top2<<<2, 256, 0, stream>>>(bsum, NBt, bsum + 256, NBc);
        scan_add2<<<dim3(NBt, 2), 256, 0, stream>>>(
            prefT, bsum, countsT, cursorT, rowinfoT, NTN,
            prefC, bsum + 256, countsC, cursorC, rowinfoC, NCN);
        place2<<<EB, 256, 0, stream>>>(dst_c2t, src_c2t, cursorT, srcAT,
                                       dst_t2c, src_t2c, cursorC, srcAC, NED);
    }

    // ---------- weight prep: fused + batched transposes ----------
    fuse_weights<<<dim3(256, 4), 256, 0, stream>>>(Wk, bk, Wv, bv, a_rel, m_rel, p_rel, Wf2, bqkv);
    copy_bq<<<4, 256, 0, stream>>>(bq, bqkv);
    // WqkvT[lt] rows: [0,256)=Wq^T, [256,512)=Wkf^T, [512,768)=Wvf^T
    convT4<<<dim3(256, 4), 256, 0, stream>>>(
        Wq, WqkvT, 65536, 196608,
        Wf2, WqkvT + 65536, 131072, 196608,
        Wf2 + 65536, WqkvT + 131072, 131072, 196608,
        Wa, WaT, 65536, 65536);
    convTb<<<(2 * 4096 + 255) / 256, 256, 0, stream>>>(W_in, WinT, 64, 256, 16384, 16384, 2);
    convTb<<<(4096 + 255) / 256, 256, 0, stream>>>(W_out, WoutT, 256, 64, 16384, 16384, 1);
    f32_to_bf16_2<<<1024, 256, 0, stream>>>(x_trans, xin0, NTN * 64 / 4,
                                            x_cc, xin1, NCN * 64 / 4);

    const int GT = (NTN + 127) / 128, GC = (NCN + 127) / 128;   // 469 / 235

    // ---------- input projections + relu (pair-merged) ----------
    gemm_wp<1, true, 64><<<GT * 4 + GC * 4, 256, 0, stream>>>(
        GT * 4,
        xin0, WinT, b_in, xs0, NTN, 256, 4, nullptr, nullptr,
        xin1, WinT + 16384, b_in + 256, xs1, NCN, 256, 4, nullptr, nullptr);

    for (int l = 0; l < 2; ++l) {
        size_t lt0 = (size_t)(l * 2 + 0), lt1 = (size_t)(l * 2 + 1);

        // fused q|k|v projections, both node types in one launch
        gemm_wp<0, true, 256><<<GT * 12 + GC * 12, 256, 0, stream>>>(
            GT * 12,
            xs0, WqkvT + lt0 * 196608, bqkv + lt0 * 768, qkv0, NTN, 768, 12, nullptr, nullptr,
            xs1, WqkvT + lt1 * 196608, bqkv + lt1 * 768, qkv1, NCN, 768, 12, nullptr, nullptr);

        // both edge phases in one launch, 2 nodes per wave
        edge_gather2<<<TBLK8 + (NCN + 7) / 8, 256, 0, stream>>>(
            qkv0, qkv1,
            rowinfoT, srcAT,
            rowinfoC, srcAC,
            agg0, agg1);

        // skip-blend output transforms, both node types in one launch
        gemm_wp<2, true, 256><<<GT * 4 + GC * 4, 256, 0, stream>>>(
            GT * 4,
            agg0, WaT + lt0 * 65536, ba + lt0 * 256, xs0, NTN, 256, 4, xs0, skip + l * 2 + 0,
            agg1, WaT + lt1 * 65536, ba + lt1 * 256, xs1, NCN, 256, 4, xs1, skip + l * 2 + 1);
    }

    // ---------- final projection + leakyrelu + row L2 normalize ----------
    {
        float* y = (float*)d_out;
        gemm_wp<3, false, 256><<<GT, 256, 0, stream>>>(
            GT,
            xs0, WoutT, b_out, y, NTN, 64, 1, nullptr, nullptr,
            xs0, WoutT, b_out, y, NTN, 64, 1, nullptr, nullptr);
        norm_rows<<<NTN / 4, 256, 0, stream>>>(y, NTN);
    }
}

// Round 15
// 452.803 us; speedup vs baseline: 1.5569x; 1.5569x over previous
//
#include <hip/hip_runtime.h>
#include <hip/hip_bf16.h>
#include <math.h>

#define NTN 60000
#define NCN 30000
#define NED 200000
// H=8, D=32, HID=256, FIN=64

typedef unsigned short u16;
typedef unsigned long long u64;
typedef __attribute__((ext_vector_type(8))) u16 u16x8;
typedef __attribute__((ext_vector_type(8))) __bf16 bf16x8;
typedef __attribute__((ext_vector_type(4))) float f32x4;

static __device__ __forceinline__ float bf2f(u16 u) {
    return __uint_as_float(((unsigned)u) << 16);
}
static __device__ __forceinline__ u16 f2bf(float f) {
    unsigned u = __float_as_uint(f);
    unsigned r = (u + 0x7fffu + ((u >> 16) & 1u)) >> 16;  // RNE
    return (u16)r;
}

// ------------------------- fill -------------------------
__global__ void fill2(unsigned* __restrict__ a, int na, unsigned* __restrict__ b, int nb) {
    int i = blockIdx.x * blockDim.x + threadIdx.x;
    int st = gridDim.x * blockDim.x;
    for (int k = i; k < na; k += st) a[k] = 0u;
    for (int k = i; k < nb; k += st) b[k] = 0u;
}

// ------------------------- conversions -------------------------
__global__ void f32_to_bf16_2(const float* __restrict__ in0, u16* __restrict__ out0, int n40,
                              const float* __restrict__ in1, u16* __restrict__ out1, int n41) {
    int i = blockIdx.x * blockDim.x + threadIdx.x;
    int stride = gridDim.x * blockDim.x;
    for (int k = i; k < n40; k += stride) {
        float4 v = ((const float4*)in0)[k];
        ushort4 o;
        o.x = f2bf(v.x); o.y = f2bf(v.y); o.z = f2bf(v.z); o.w = f2bf(v.w);
        ((ushort4*)out0)[k] = o;
    }
    for (int k = i; k < n41; k += stride) {
        float4 v = ((const float4*)in1)[k];
        ushort4 o;
        o.x = f2bf(v.x); o.y = f2bf(v.y); o.z = f2bf(v.z); o.w = f2bf(v.w);
        ((ushort4*)out1)[k] = o;
    }
}

// batched: out[m][n][k] = bf16(in[m][k][n]) with per-matrix strides.
__global__ void convTb(const float* __restrict__ in, u16* __restrict__ out,
                       int K, int N, int inStride, int outStride, int nm) {
    int idx = blockIdx.x * blockDim.x + threadIdx.x;
    int per = N * (K >> 2);
    int total = per * nm;
    if (idx >= total) return;
    int mat = idx / per, rem = idx - mat * per;
    int k4 = rem / N, n = rem - k4 * N;
    int k = k4 * 4;
    const float* src = in + (size_t)mat * inStride;
    u16* dst = out + (size_t)mat * outStride;
    ushort4 o;
    o.x = f2bf(src[(size_t)(k + 0) * N + n]);
    o.y = f2bf(src[(size_t)(k + 1) * N + n]);
    o.z = f2bf(src[(size_t)(k + 2) * N + n]);
    o.w = f2bf(src[(size_t)(k + 3) * N + n]);
    *(ushort4*)(dst + (size_t)n * K + k) = o;
}

// 4 groups of 256x256 (nm=4 each) transposes in one launch; blockIdx.y picks group.
__global__ void convT4(const float* __restrict__ s0, u16* __restrict__ d0, int is0, int os0,
                       const float* __restrict__ s1, u16* __restrict__ d1, int is1, int os1,
                       const float* __restrict__ s2, u16* __restrict__ d2, int is2, int os2,
                       const float* __restrict__ s3, u16* __restrict__ d3, int is3, int os3) {
    const float* in; u16* out; int inStride, outStride;
    switch (blockIdx.y) {
        case 0: in = s0; out = d0; inStride = is0; outStride = os0; break;
        case 1: in = s1; out = d1; inStride = is1; outStride = os1; break;
        case 2: in = s2; out = d2; inStride = is2; outStride = os2; break;
        default: in = s3; out = d3; inStride = is3; outStride = os3; break;
    }
    int idx = blockIdx.x * blockDim.x + threadIdx.x;
    const int per = 256 * 64;            // N * K/4
    int mat = idx / per, rem = idx - mat * per;
    int k4 = rem >> 8, n = rem & 255;
    int k = k4 * 4;
    const float* src = in + (size_t)mat * inStride;
    u16* dst = out + (size_t)mat * outStride;
    ushort4 o;
    o.x = f2bf(src[(size_t)(k + 0) * 256 + n]);
    o.y = f2bf(src[(size_t)(k + 1) * 256 + n]);
    o.z = f2bf(src[(size_t)(k + 2) * 256 + n]);
    o.w = f2bf(src[(size_t)(k + 3) * 256 + n]);
    *(ushort4*)(dst + (size_t)n * 256 + k) = o;
}

__global__ void copy_bq(const float* __restrict__ bq, float* __restrict__ bqkv) {
    int lt = blockIdx.x;
    bqkv[lt * 768 + threadIdx.x] = bq[lt * 256 + threadIdx.x];
}

// --------------------- weight fusion (all 4 lt in one launch) ---------------------
__global__ __launch_bounds__(256) void fuse_weights(
    const float* __restrict__ Wk, const float* __restrict__ bk,
    const float* __restrict__ Wv, const float* __restrict__ bv,
    const float* __restrict__ a_rel, const float* __restrict__ m_rel,
    const float* __restrict__ p_rel,
    float* __restrict__ Wf2, float* __restrict__ bqkv)
{
    __shared__ float kw[256], vw[256];
    const int c = blockIdx.x, lt = blockIdx.y, tid = threadIdx.x;
    const int l = lt >> 1, t = lt & 1;
    const int lr = l * 2 + (t == 1 ? 0 : 1);     // relation where type t is the SOURCE
    const float* WkP = Wk + (size_t)lt * 65536;
    const float* WvP = Wv + (size_t)lt * 65536;
    const float* ar = a_rel + (size_t)lr * 8192;
    const float* mr = m_rel + (size_t)lr * 8192;
    kw[tid] = WkP[c * 256 + tid];
    vw[tid] = WvP[c * 256 + tid];
    __syncthreads();
    const int h = tid >> 5, e = tid & 31;
    const float s = p_rel[lr * 8 + h] * 0.17677669529663687f;  // 1/sqrt(32)
    float ak = 0.f, av = 0.f;
#pragma unroll 8
    for (int d = 0; d < 32; ++d) {
        ak += kw[h * 32 + d] * ar[h * 1024 + d * 32 + e];
        av += vw[h * 32 + d] * mr[h * 1024 + d * 32 + e];
    }
    float* WkfP = Wf2 + (size_t)lt * 131072;
    WkfP[c * 256 + tid] = ak * s;
    WkfP[65536 + c * 256 + tid] = av;
    if (c == 0) {
        const float* bkP = bk + (size_t)lt * 256;
        const float* bvP = bv + (size_t)lt * 256;
        float bka = 0.f, bva = 0.f;
#pragma unroll 8
        for (int d = 0; d < 32; ++d) {
            bka += bkP[h * 32 + d] * ar[h * 1024 + d * 32 + e];
            bva += bvP[h * 32 + d] * mr[h * 1024 + d * 32 + e];
        }
        bqkv[lt * 768 + 256 + tid] = bka * s;
        bqkv[lt * 768 + 512 + tid] = bva;
    }
}

// ------------------------- MFMA GEMM (pair-merged; R11-proven core) -------------------------
// Two back-to-back GEMMs in one grid: blocks [0,nblk0) run set 0, rest set 1.
// Per set: C[M, NY*BN] = epi(A[M,K](bf16) @ WT^T(bf16) + bias).
// 64 x BN tile, BK=64, 4 waves, double-buffered LDS, counted vmcnt; 32KB LDS.
// EPI: 0=none, 1=relu, 2=skip-blend(bf16 out), 3=leakyrelu+row-L2-norm (f32 out,
// requires BN == total N == ldC so a block owns full rows).
template <int EPI, int BN, bool OBF>
__global__ __launch_bounds__(256) void gemm_mfma2(
    int nblk0,
    const u16* __restrict__ A0, const u16* __restrict__ W0, const float* __restrict__ b0,
    void* __restrict__ C0, int M0, int ldC0, int NY0,
    const u16* __restrict__ xr0, const float* __restrict__ sk0,
    const u16* __restrict__ A1, const u16* __restrict__ W1, const float* __restrict__ b1,
    void* __restrict__ C1, int M1, int ldC1, int NY1,
    const u16* __restrict__ xr1, const float* __restrict__ sk1,
    int K)
{
    constexpr int ASZ = 64 * 64;
    constexpr int BSZ = BN * 64;
    constexpr int NF = BN / 32;
    __shared__ u16 smem[2 * (ASZ + BSZ)];
    u16* As0 = smem;             u16* Bs0 = smem + ASZ;
    u16* As1 = smem + ASZ + BSZ; u16* Bs1 = As1 + ASZ;

    // bijective XCD swizzle (m204) over the merged grid
    const int nwg = gridDim.x;
    const int bid = blockIdx.x;
    const int q8 = nwg >> 3, r8 = nwg & 7;
    const int xcd = bid & 7, pos = bid >> 3;
    const int lbid = (xcd < r8) ? xcd * (q8 + 1) + pos
                                : r8 * (q8 + 1) + (xcd - r8) * q8 + pos;

    const u16* A; const u16* WT; const float* bias; void* Cv;
    int M, ldC, NY, sb; const u16* xres; const float* skipPtr;
    if (lbid < nblk0) {
        A = A0; WT = W0; bias = b0; Cv = C0; M = M0; ldC = ldC0; NY = NY0;
        xres = xr0; skipPtr = sk0; sb = lbid;
    } else {
        A = A1; WT = W1; bias = b1; Cv = C1; M = M1; ldC = ldC1; NY = NY1;
        xres = xr1; skipPtr = sk1; sb = lbid - nblk0;
    }
    const int bx = sb / NY, by = sb - bx * NY;
    const int m0 = bx * 64, n0 = by * BN;

    const int tid = threadIdx.x;
    const int wave = tid >> 6, lane = tid & 63;
    const int wm = (wave >> 1) * 32, wn = (wave & 1) * (BN / 2);
    f32x4 acc[2][NF];
#pragma unroll
    for (int i = 0; i < 2; ++i)
#pragma unroll
        for (int j = 0; j < NF; ++j) acc[i][j] = (f32x4){0.f, 0.f, 0.f, 0.f};

    const int sr = lane >> 3;
    const int sl = lane & 7;

    auto stage = [&](int k0, u16* Ad, u16* Bd) {
#pragma unroll
        for (int i = 0; i < 2; ++i) {
            int rb = wave * 16 + i * 8;
            int r = rb + sr;
            int gr = m0 + r; gr = gr < M ? gr : M - 1;
            const u16* gp = A + (size_t)gr * K + k0 + ((sl ^ sr) << 3);
            __builtin_amdgcn_global_load_lds(
                (const __attribute__((address_space(1))) void*)gp,
                (__attribute__((address_space(3))) void*)(Ad + rb * 64), 16, 0, 0);
        }
#pragma unroll
        for (int i = 0; i < NF; ++i) {
            int rb = wave * (BN / 4) + i * 8;
            int r = rb + sr;
            const u16* gp = WT + (size_t)(n0 + r) * K + k0 + ((sl ^ sr) << 3);
            __builtin_amdgcn_global_load_lds(
                (const __attribute__((address_space(1))) void*)gp,
                (__attribute__((address_space(3))) void*)(Bd + rb * 64), 16, 0, 0);
        }
    };

    auto compute = [&](const u16* Ab, const u16* Bb) {
#pragma unroll
        for (int kx = 0; kx < 2; ++kx) {
            bf16x8 af[2], bfr[NF];
#pragma unroll
            for (int mf = 0; mf < 2; ++mf) {
                int r = wm + mf * 16 + (lane & 15);
                int slot = (lane >> 4) + kx * 4;
                af[mf] = __builtin_bit_cast(bf16x8,
                    *(const u16x8*)(Ab + r * 64 + ((slot ^ (r & 7)) << 3)));
            }
#pragma unroll
            for (int nf = 0; nf < NF; ++nf) {
                int r = wn + nf * 16 + (lane & 15);
                int slot = (lane >> 4) + kx * 4;
                bfr[nf] = __builtin_bit_cast(bf16x8,
                    *(const u16x8*)(Bb + r * 64 + ((slot ^ (r & 7)) << 3)));
            }
#pragma unroll
            for (int mf = 0; mf < 2; ++mf)
#pragma unroll
                for (int nf = 0; nf < NF; ++nf)
                    acc[mf][nf] = __builtin_amdgcn_mfma_f32_16x16x32_bf16(
                        af[mf], bfr[nf], acc[mf][nf], 0, 0, 0);
        }
    };

    const int nt = K >> 6;
    stage(0, As0, Bs0);
    for (int t = 0; t < nt; ++t) {
        const bool pb = t & 1;
        if (t + 1 < nt) {
            stage((t + 1) << 6, pb ? As0 : As1, pb ? Bs0 : Bs1);
            __builtin_amdgcn_sched_barrier(0);
            if constexpr (BN == 128) asm volatile("s_waitcnt vmcnt(6)" ::: "memory");
            else                     asm volatile("s_waitcnt vmcnt(4)" ::: "memory");
        } else {
            asm volatile("s_waitcnt vmcnt(0)" ::: "memory");
        }
        __builtin_amdgcn_s_barrier();
        __builtin_amdgcn_sched_barrier(0);
        compute(pb ? As1 : As0, pb ? Bs1 : Bs0);
        __builtin_amdgcn_sched_barrier(0);
        __builtin_amdgcn_s_barrier();
        __builtin_amdgcn_sched_barrier(0);   // fence: next stage must not hoist above
    }

    float beta = 0.f;
    if (EPI == 2) beta = 1.f / (1.f + expf(-skipPtr[0]));

    if constexpr (EPI == 3) {
        // fused leakyrelu + row-L2-normalize + f32 store. Block owns full rows (BN == ldC).
        constexpr int CLDF = BN + 4;
        float* Cf = (float*)smem;   // 64 * 68 * 4 = 17.4 KB <= 32 KB
#pragma unroll
        for (int nf = 0; nf < NF; ++nf) {
            int col = wn + nf * 16 + (lane & 15);
            float bs = bias[n0 + col];
#pragma unroll
            for (int mf = 0; mf < 2; ++mf) {
#pragma unroll
                for (int j = 0; j < 4; ++j) {
                    int row = wm + mf * 16 + (lane >> 4) * 4 + j;
                    float c = acc[mf][nf][j] + bs;
                    c = (c > 0.f) ? c : 0.2f * c;
                    Cf[row * CLDF + col] = c;
                }
            }
        }
        __syncthreads();
        // 4 threads per row; quad shfl reduce of sum-of-squares; coalesced f32 writes
        int row = tid >> 2, q = tid & 3;
        float4 v[4];
        float ss = 0.f;
#pragma unroll
        for (int i = 0; i < 4; ++i) {
            v[i] = *(const float4*)(Cf + row * CLDF + q * 16 + i * 4);
            ss += v[i].x * v[i].x + v[i].y * v[i].y + v[i].z * v[i].z + v[i].w * v[i].w;
        }
        ss += __shfl_xor(ss, 1);
        ss += __shfl_xor(ss, 2);
        float nrm = sqrtf(ss);
        float inv = 1.f / fmaxf(nrm, 1e-12f);
        int grow = m0 + row;
        if (grow < M) {
            float* dst = (float*)Cv + (size_t)grow * ldC + q * 16;
#pragma unroll
            for (int i = 0; i < 4; ++i) {
                float4 o;
                o.x = v[i].x * inv; o.y = v[i].y * inv;
                o.z = v[i].z * inv; o.w = v[i].w * inv;
                *(float4*)(dst + i * 4) = o;
            }
        }
    } else if constexpr (OBF) {
        constexpr int CLD = BN + 8;
        u16* Ct = smem;
#pragma unroll
        for (int nf = 0; nf < NF; ++nf) {
            int col = wn + nf * 16 + (lane & 15);
            int gcol = n0 + col;
            float bs = bias[gcol];
#pragma unroll
            for (int mf = 0; mf < 2; ++mf) {
#pragma unroll
                for (int j = 0; j < 4; ++j) {
                    int row = wm + mf * 16 + (lane >> 4) * 4 + j;
                    int grow = m0 + row;
                    int gr2 = grow < M ? grow : 0;
                    float c = acc[mf][nf][j] + bs;
                    if (EPI == 1) c = fmaxf(c, 0.f);
                    if (EPI == 2) c = beta * c + (1.f - beta) * bf2f(xres[(size_t)gr2 * ldC + gcol]);
                    Ct[row * CLD + col] = f2bf(c);
                }
            }
        }
        __syncthreads();   // full lgkm drain + fence: cross-wave LDS handoff
        int row = tid >> 2, c0 = (tid & 3) * (BN / 4);
        int grow = m0 + row;
        if (grow < M) {
            u16* dst = (u16*)Cv + (size_t)grow * ldC + n0 + c0;
            const u16* src = Ct + row * CLD + c0;
#pragma unroll
            for (int i = 0; i < BN / 32; ++i)
                *(u16x8*)(dst + i * 8) = *(const u16x8*)(src + i * 8);
        }
    } else {
#pragma unroll
        for (int nf = 0; nf < NF; ++nf) {
            int gcol = n0 + wn + nf * 16 + (lane & 15);
            float bs = bias[gcol];
#pragma unroll
            for (int mf = 0; mf < 2; ++mf) {
#pragma unroll
                for (int j = 0; j < 4; ++j) {
                    int grow = m0 + wm + mf * 16 + (lane >> 4) * 4 + j;
                    if (grow >= M) continue;
                    float c = acc[mf][nf][j] + bs;
                    if (EPI == 1) c = fmaxf(c, 0.f);
                    ((float*)Cv)[(size_t)grow * ldC + gcol] = c;
                }
            }
        }
    }
}

// ------------------------- CSR build (both relations per launch) -------------------------
__global__ void hist2(const int* __restrict__ d0, unsigned* __restrict__ c0,
                      const int* __restrict__ d1, unsigned* __restrict__ c1, int E) {
    int e = blockIdx.x * blockDim.x + threadIdx.x;
    if (e < E) {
        atomicAdd(&c0[d0[e]], 1u);
        atomicAdd(&c1[d1[e]], 1u);
    }
}

__global__ __launch_bounds__(256) void scan_blocks2(
    const unsigned* __restrict__ c0, unsigned* __restrict__ p0, unsigned* __restrict__ bs0, int N0,
    const unsigned* __restrict__ c1, unsigned* __restrict__ p1, unsigned* __restrict__ bs1, int N1)
{
    const unsigned* counts = blockIdx.y ? c1 : c0;
    unsigned* pref = blockIdx.y ? p1 : p0;
    unsigned* bsum = blockIdx.y ? bs1 : bs0;
    int N = blockIdx.y ? N1 : N0;
    if ((int)blockIdx.x * 256 >= N) return;   // block-uniform early-out
    __shared__ unsigned tmp[256];
    int i = blockIdx.x * 256 + threadIdx.x;
    unsigned v = (i < N) ? counts[i] : 0u;
    tmp[threadIdx.x] = v;
    __syncthreads();
    for (int off = 1; off < 256; off <<= 1) {
        unsigned t = (threadIdx.x >= off) ? tmp[threadIdx.x - off] : 0u;
        __syncthreads();
        tmp[threadIdx.x] += t;
        __syncthreads();
    }
    if (i < N) pref[i] = tmp[threadIdx.x] - v;  // exclusive
    if (threadIdx.x == 255) bsum[blockIdx.x] = tmp[255];
}

__global__ __launch_bounds__(256) void scan_top2(
    unsigned* __restrict__ bs0, int NB0, unsigned* __restrict__ bs1, int NB1)
{
    unsigned* bsum = blockIdx.x ? bs1 : bs0;
    int NB = blockIdx.x ? NB1 : NB0;
    __shared__ unsigned tmp[256];
    unsigned v = ((int)threadIdx.x < NB) ? bsum[threadIdx.x] : 0u;
    tmp[threadIdx.x] = v;
    __syncthreads();
    for (int off = 1; off < 256; off <<= 1) {
        unsigned t = (threadIdx.x >= off) ? tmp[threadIdx.x - off] : 0u;
        __syncthreads();
        tmp[threadIdx.x] += t;
        __syncthreads();
    }
    if ((int)threadIdx.x < NB) bsum[threadIdx.x] = tmp[threadIdx.x] - v;  // exclusive
}

// packs rowstart|deg into one u64 per node (single load in edge kernel)
__global__ void scan_add2(
    const unsigned* __restrict__ p0, const unsigned* __restrict__ bs0,
    const unsigned* __restrict__ c0, unsigned* __restrict__ cur0, u64* __restrict__ ri0, int N0,
    const unsigned* __restrict__ p1, const unsigned* __restrict__ bs1,
    const unsigned* __restrict__ c1, unsigned* __restrict__ cur1, u64* __restrict__ ri1, int N1)
{
    const unsigned* pref = blockIdx.y ? p1 : p0;
    const unsigned* bsum = blockIdx.y ? bs1 : bs0;
    const unsigned* counts = blockIdx.y ? c1 : c0;
    unsigned* cursor = blockIdx.y ? cur1 : cur0;
    u64* rowinfo = blockIdx.y ? ri1 : ri0;
    int N = blockIdx.y ? N1 : N0;
    int i = blockIdx.x * 256 + threadIdx.x;
    if (i < N) {
        unsigned s = pref[i] + bsum[blockIdx.x];
        cursor[i] = s;
        rowinfo[i] = (u64)s | ((u64)counts[i] << 32);
    }
}

// stores PRE-MULTIPLIED row offset (src*768, u16 units).
__global__ void place2(const int* __restrict__ d0, const int* __restrict__ s0,
                       unsigned* __restrict__ cur0, unsigned* __restrict__ o0,
                       const int* __restrict__ d1, const int* __restrict__ s1,
                       unsigned* __restrict__ cur1, unsigned* __restrict__ o1, int E) {
    int e = blockIdx.x * blockDim.x + threadIdx.x;
    if (e < E) {
        unsigned p = atomicAdd(&cur0[d0[e]], 1u);
        o0[p] = (unsigned)s0[e] * 768u;
        unsigned q = atomicAdd(&cur1[d1[e]], 1u);
        o1[q] = (unsigned)s1[e] * 768u;
    }
}

// ------------------------- fused edge gather (2 nodes per wave) -------------------------
// Each 32-lane HALF owns ONE dst node (32 lanes x 16B = full 256-wide row):
// no cross-half merge; q-prep/softmax-finish/gelu/store serve 2 nodes per
// wave instruction. Online softmax w/ defer-max ballot fast path.
#define TBLK8 ((NTN + 7) / 8)
__global__ __launch_bounds__(256) void edge_gather2(
    const u16* __restrict__ qkvT, const u16* __restrict__ qkvC,
    const u64* __restrict__ riT, const unsigned* __restrict__ srcT,
    const u64* __restrict__ riC, const unsigned* __restrict__ srcC,
    u16* __restrict__ aggT, u16* __restrict__ aggC)
{
    const int b = blockIdx.x;
    const bool isT = b < TBLK8;
    const int lane = threadIdx.x & 63;
    const int lq = lane & 31;
    const int n = (((isT ? b : b - TBLK8) << 2) + (int)(threadIdx.x >> 6)) * 2 + (lane >> 5);

    const u16* qkv_d = isT ? qkvT : qkvC;
    const u16* qkv_s = isT ? qkvC : qkvT;
    const u64* ri = isT ? riT : riC;
    const unsigned* srcarr = isT ? srcT : srcC;
    u16* agg = isT ? aggT : aggC;

    const u64 rinfo = ri[n];
    const unsigned start = (unsigned)rinfo;
    const unsigned deg = (unsigned)(rinfo >> 32);
    u16* outp = &agg[(size_t)n * 256 + lq * 8];

    if (deg == 0) {
        *(u16x8*)outp = (u16x8){0, 0, 0, 0, 0, 0, 0, 0};
        return;
    }

    u16x8 qv = *(const u16x8*)&qkv_d[(size_t)n * 768 + lq * 8];
    float qf[8];
#pragma unroll
    for (int i = 0; i < 8; ++i) qf[i] = bf2f(qv[i]);

    const u16* kvb = qkv_s + 256 + lq * 8;   // k section base (lane folded); v at +256
    float m = -INFINITY, s = 0.f;
    float acc[8] = {0.f, 0.f, 0.f, 0.f, 0.f, 0.f, 0.f, 0.f};

    unsigned off = srcarr[start];
    u16x8 kr = *(const u16x8*)(kvb + off);
    u16x8 vr = *(const u16x8*)(kvb + off + 256);
    for (unsigned j = 0;;) {
        const bool more = (j + 1 < deg);
        u16x8 kr_n, vr_n;
        if (more) {
            unsigned off2 = srcarr[start + j + 1];
            kr_n = *(const u16x8*)(kvb + off2);
            vr_n = *(const u16x8*)(kvb + off2 + 256);
        }
        float kf[8];
#pragma unroll
        for (int i = 0; i < 8; ++i) kf[i] = bf2f(kr[i]);
        float p = qf[0] * kf[0] + qf[1] * kf[1] + qf[2] * kf[2] + qf[3] * kf[3]
                + qf[4] * kf[4] + qf[5] * kf[5] + qf[6] * kf[6] + qf[7] * kf[7];
        p += __shfl_xor(p, 1);
        p += __shfl_xor(p, 2);          // quad = the 4 lanes of this head (within half)
        float vf[8];
#pragma unroll
        for (int i = 0; i < 8; ++i) vf[i] = bf2f(vr[i]);
        if (__ballot(p > m) == 0ull) {
            float wv = __expf(p - m);
            s += wv;
#pragma unroll
            for (int i = 0; i < 8; ++i) acc[i] += wv * vf[i];
        } else {
            float mn = fmaxf(m, p);
            float sc = __expf(m - mn);  // 0 on first iteration (m = -inf)
            float wv = __expf(p - mn);
            s = s * sc + wv;
#pragma unroll
            for (int i = 0; i < 8; ++i) acc[i] = acc[i] * sc + wv * vf[i];
            m = mn;
        }
        if (!more) break;
        kr = kr_n; vr = vr_n; ++j;
    }

    float inv = 1.f / (s + 1e-16f);
    u16x8 ov;
#pragma unroll
    for (int i = 0; i < 8; ++i) {
        float x = acc[i] * inv;
        // gelu(x) ~= 0.5x(1+tanh(0.79788456(x+0.044715x^3))), tanh via expf
        float y2 = 1.5957691216f * x + 0.0713548163f * x * x * x;  // 2*y
        float e = __expf(y2);
        float t = 1.f - 2.f / (e + 1.f);
        ov[i] = f2bf(0.5f * x * (1.f + t));
    }
    *(u16x8*)outp = ov;
}

// ------------------------- launch -------------------------
extern "C" void kernel_launch(void* const* d_in, const int* in_sizes, int n_in,
                              void* d_out, int out_size, void* d_ws, size_t ws_size,
                              hipStream_t stream)
{
    const float* x_trans = (const float*)d_in[0];
    const float* x_cc    = (const float*)d_in[1];
    const int* src_c2t   = (const int*)d_in[2];
    const int* dst_c2t   = (const int*)d_in[3];
    const int* src_t2c   = (const int*)d_in[4];
    const int* dst_t2c   = (const int*)d_in[5];
    const float* W_in = (const float*)d_in[6];
    const float* b_in = (const float*)d_in[7];
    const float* Wk   = (const float*)d_in[8];
    const float* bk   = (const float*)d_in[9];
    const float* Wq   = (const float*)d_in[10];
    const float* bq   = (const float*)d_in[11];
    const float* Wv   = (const float*)d_in[12];
    const float* bv   = (const float*)d_in[13];
    const float* Wa   = (const float*)d_in[14];
    const float* ba   = (const float*)d_in[15];
    const float* a_rel = (const float*)d_in[16];
    const float* m_rel = (const float*)d_in[17];
    const float* p_rel = (const float*)d_in[18];
    const float* skip  = (const float*)d_in[19];
    const float* W_out = (const float*)d_in[20];
    const float* b_out = (const float*)d_in[21];

    // ---------- workspace layout (~251 MB) ----------
    char* w = (char*)d_ws;
    auto alloc = [&](size_t bytes) { char* p = w; w += (bytes + 255) & ~(size_t)255; return p; };
    u16* xs0  = (u16*)alloc((size_t)NTN * 256 * 2);
    u16* xs1  = (u16*)alloc((size_t)NCN * 256 * 2);
    u16* xin0 = (u16*)alloc((size_t)NTN * 64 * 2);
    u16* xin1 = (u16*)alloc((size_t)NCN * 64 * 2);
    u16* qkv0 = (u16*)alloc((size_t)NTN * 768 * 2);   // 92.2 MB
    u16* qkv1 = (u16*)alloc((size_t)NCN * 768 * 2);   // 46.1 MB
    u16* agg0 = (u16*)alloc((size_t)NTN * 256 * 2);
    u16* agg1 = (u16*)alloc((size_t)NCN * 256 * 2);
    u16* WinT = (u16*)alloc((size_t)2 * 16384 * 2);
    u16* WqkvT= (u16*)alloc((size_t)4 * 196608 * 2);  // [768][256] per lt
    u16* WaT  = (u16*)alloc((size_t)4 * 65536 * 2);
    u16* WoutT= (u16*)alloc((size_t)16384 * 2);
    float* Wf2 = (float*)alloc((size_t)4 * 131072 * 4); // [lt][kf|vf] f32 staging
    float* bqkv = (float*)alloc((size_t)4 * 768 * 4);
    unsigned* countsT   = (unsigned*)alloc((size_t)NTN * 4);
    unsigned* prefT     = (unsigned*)alloc((size_t)NTN * 4);
    unsigned* cursorT   = (unsigned*)alloc((size_t)NTN * 4);
    u64* rowinfoT       = (u64*)alloc((size_t)NTN * 8);
    unsigned* srcAT     = (unsigned*)alloc((size_t)NED * 4);
    unsigned* countsC   = (unsigned*)alloc((size_t)NCN * 4);
    unsigned* prefC     = (unsigned*)alloc((size_t)NCN * 4);
    unsigned* cursorC   = (unsigned*)alloc((size_t)NCN * 4);
    u64* rowinfoC       = (u64*)alloc((size_t)NCN * 8);
    unsigned* srcAC     = (unsigned*)alloc((size_t)NED * 4);
    unsigned* bsum      = (unsigned*)alloc((size_t)2 * 256 * 4);
    (void)ws_size; (void)in_sizes; (void)n_in; (void)out_size;

    // ---------- CSR builds (both relations per launch; shared by both layers) ----------
    {
        const int EB = (NED + 255) / 256;
        const int NBt = (NTN + 255) / 256, NBc = (NCN + 255) / 256;
        fill2<<<256, 256, 0, stream>>>(countsT, NTN, countsC, NCN);
        hist2<<<EB, 256, 0, stream>>>(dst_c2t, countsT, dst_t2c, countsC, NED);
        scan_blocks2<<<dim3(NBt, 2), 256, 0, stream>>>(countsT, prefT, bsum, NTN,
                                                       countsC, prefC, bsum + 256, NCN);
        scan_top2<<<2, 256, 0, stream>>>(bsum, NBt, bsum + 256, NBc);
        scan_add2<<<dim3(NBt, 2), 256, 0, stream>>>(
            prefT, bsum, countsT, cursorT, rowinfoT, NTN,
            prefC, bsum + 256, countsC, cursorC, rowinfoC, NCN);
        place2<<<EB, 256, 0, stream>>>(dst_c2t, src_c2t, cursorT, srcAT,
                                       dst_t2c, src_t2c, cursorC, srcAC, NED);
    }

    // ---------- weight prep: fused + batched transposes ----------
    fuse_weights<<<dim3(256, 4), 256, 0, stream>>>(Wk, bk, Wv, bv, a_rel, m_rel, p_rel, Wf2, bqkv);
    copy_bq<<<4, 256, 0, stream>>>(bq, bqkv);
    // WqkvT[lt] rows: [0,256)=Wq^T, [256,512)=Wkf^T, [512,768)=Wvf^T
    convT4<<<dim3(256, 4), 256, 0, stream>>>(
        Wq, WqkvT, 65536, 196608,
        Wf2, WqkvT + 65536, 131072, 196608,
        Wf2 + 65536, WqkvT + 131072, 131072, 196608,
        Wa, WaT, 65536, 65536);
    convTb<<<(2 * 4096 + 255) / 256, 256, 0, stream>>>(W_in, WinT, 64, 256, 16384, 16384, 2);
    convTb<<<(4096 + 255) / 256, 256, 0, stream>>>(W_out, WoutT, 256, 64, 16384, 16384, 1);
    f32_to_bf16_2<<<1024, 256, 0, stream>>>(x_trans, xin0, NTN * 64 / 4,
                                            x_cc, xin1, NCN * 64 / 4);

    const int GT = (NTN + 63) / 64, GC = (NCN + 63) / 64;   // 938 / 469

    // ---------- input projections + relu (pair-merged) ----------
    gemm_mfma2<1, 64, true><<<GT * 4 + GC * 4, 256, 0, stream>>>(
        GT * 4,
        xin0, WinT, b_in, xs0, NTN, 256, 4, nullptr, nullptr,
        xin1, WinT + 16384, b_in + 256, xs1, NCN, 256, 4, nullptr, nullptr,
        64);

    for (int l = 0; l < 2; ++l) {
        size_t lt0 = (size_t)(l * 2 + 0), lt1 = (size_t)(l * 2 + 1);

        // fused q|k|v projections, both node types in one launch
        gemm_mfma2<0, 64, true><<<GT * 12 + GC * 12, 256, 0, stream>>>(
            GT * 12,
            xs0, WqkvT + lt0 * 196608, bqkv + lt0 * 768, qkv0, NTN, 768, 12, nullptr, nullptr,
            xs1, WqkvT + lt1 * 196608, bqkv + lt1 * 768, qkv1, NCN, 768, 12, nullptr, nullptr,
            256);

        // both edge phases in one launch, 2 nodes per wave
        edge_gather2<<<TBLK8 + (NCN + 7) / 8, 256, 0, stream>>>(
            qkv0, qkv1,
            rowinfoT, srcAT,
            rowinfoC, srcAC,
            agg0, agg1);

        // skip-blend output transforms, both node types in one launch
        gemm_mfma2<2, 64, true><<<GT * 4 + GC * 4, 256, 0, stream>>>(
            GT * 4,
            agg0, WaT + lt0 * 65536, ba + lt0 * 256, xs0, NTN, 256, 4, xs0, skip + l * 2 + 0,
            agg1, WaT + lt1 * 65536, ba + lt1 * 256, xs1, NCN, 256, 4, xs1, skip + l * 2 + 1,
            256);
    }

    // ---------- final projection + leakyrelu + row L2 normalize (fused) ----------
    {
        float* y = (float*)d_out;
        gemm_mfma2<3, 64, false><<<GT, 256, 0, stream>>>(
            GT,
            xs0, WoutT, b_out, y, NTN, 64, 1, nullptr, nullptr,
            xs0, WoutT, b_out, y, NTN, 64, 1, nullptr, nullptr,
            256);
    }
}

// Round 16
// 438.175 us; speedup vs baseline: 1.6089x; 1.0334x over previous
//
#include <hip/hip_runtime.h>
#include <hip/hip_bf16.h>
#include <math.h>

#define NTN 60000
#define NCN 30000
#define NED 200000
// H=8, D=32, HID=256, FIN=64

typedef unsigned short u16;
typedef unsigned long long u64;
typedef __attribute__((ext_vector_type(8))) u16 u16x8;
typedef __attribute__((ext_vector_type(8))) __bf16 bf16x8;
typedef __attribute__((ext_vector_type(4))) float f32x4;

static __device__ __forceinline__ float bf2f(u16 u) {
    return __uint_as_float(((unsigned)u) << 16);
}
static __device__ __forceinline__ u16 f2bf(float f) {
    unsigned u = __float_as_uint(f);
    unsigned r = (u + 0x7fffu + ((u >> 16) & 1u)) >> 16;  // RNE
    return (u16)r;
}

// ------------------- mega prep 1: fills + fuse + small transposes + input conv -------------------
// block ranges: [0,128) fill counts | [128,1152) fuse_weights (c=(sb-128)&255, lt=(sb-128)>>8)
// [1152,1184) Win transpose | [1184,1200) Wout transpose | [1200,1500) x f32->bf16
__global__ __launch_bounds__(256) void prep1(
    unsigned* __restrict__ countsT, unsigned* __restrict__ countsC,
    const float* __restrict__ Wk, const float* __restrict__ bk,
    const float* __restrict__ Wv, const float* __restrict__ bv,
    const float* __restrict__ a_rel, const float* __restrict__ m_rel,
    const float* __restrict__ p_rel,
    float* __restrict__ Wf2, float* __restrict__ bqkv, const float* __restrict__ bq,
    const float* __restrict__ W_in, u16* __restrict__ WinT,
    const float* __restrict__ W_out, u16* __restrict__ WoutT,
    const float* __restrict__ x_trans, u16* __restrict__ xin0,
    const float* __restrict__ x_cc, u16* __restrict__ xin1)
{
    __shared__ float kw[256], vw[256];
    const int sb = blockIdx.x, tid = threadIdx.x;
    if (sb < 128) {
        int i = sb * 256 + tid, st = 128 * 256;
        for (int k = i; k < NTN; k += st) countsT[k] = 0u;
        for (int k = i; k < NCN; k += st) countsC[k] = 0u;
    } else if (sb < 1152) {
        const int c = (sb - 128) & 255, lt = (sb - 128) >> 8;
        const int l = lt >> 1, t = lt & 1;
        const int lr = l * 2 + (t == 1 ? 0 : 1);     // relation where type t is the SOURCE
        const float* WkP = Wk + (size_t)lt * 65536;
        const float* WvP = Wv + (size_t)lt * 65536;
        const float* ar = a_rel + (size_t)lr * 8192;
        const float* mr = m_rel + (size_t)lr * 8192;
        kw[tid] = WkP[c * 256 + tid];
        vw[tid] = WvP[c * 256 + tid];
        __syncthreads();
        const int h = tid >> 5, e = tid & 31;
        const float s = p_rel[lr * 8 + h] * 0.17677669529663687f;  // 1/sqrt(32)
        float ak = 0.f, av = 0.f;
#pragma unroll 8
        for (int d = 0; d < 32; ++d) {
            ak += kw[h * 32 + d] * ar[h * 1024 + d * 32 + e];
            av += vw[h * 32 + d] * mr[h * 1024 + d * 32 + e];
        }
        float* WkfP = Wf2 + (size_t)lt * 131072;
        WkfP[c * 256 + tid] = ak * s;
        WkfP[65536 + c * 256 + tid] = av;
        if (c == 0) {
            const float* bkP = bk + (size_t)lt * 256;
            const float* bvP = bv + (size_t)lt * 256;
            float bka = 0.f, bva = 0.f;
#pragma unroll 8
            for (int d = 0; d < 32; ++d) {
                bka += bkP[h * 32 + d] * ar[h * 1024 + d * 32 + e];
                bva += bvP[h * 32 + d] * mr[h * 1024 + d * 32 + e];
            }
            bqkv[lt * 768 + tid] = bq[lt * 256 + tid];
            bqkv[lt * 768 + 256 + tid] = bka * s;
            bqkv[lt * 768 + 512 + tid] = bva;
        }
    } else if (sb < 1184) {
        // Win^T: 2 matrices [64][256] -> [256][64]; per = 256*16 = 4096 ushort4
        int idx = (sb - 1152) * 256 + tid;
        int mat = idx >> 12, rem = idx & 4095;
        int k4 = rem >> 8, n = rem & 255;
        int k = k4 * 4;
        const float* src = W_in + (size_t)mat * 16384;
        u16* dst = WinT + (size_t)mat * 16384;
        ushort4 o;
        o.x = f2bf(src[(size_t)(k + 0) * 256 + n]);
        o.y = f2bf(src[(size_t)(k + 1) * 256 + n]);
        o.z = f2bf(src[(size_t)(k + 2) * 256 + n]);
        o.w = f2bf(src[(size_t)(k + 3) * 256 + n]);
        *(ushort4*)(dst + (size_t)n * 64 + k) = o;
    } else if (sb < 1200) {
        // Wout^T: [256][64] -> [64][256]; per = 64*64 = 4096 ushort4
        int idx = (sb - 1184) * 256 + tid;
        int k4 = idx >> 6, n = idx & 63;
        int k = k4 * 4;
        ushort4 o;
        o.x = f2bf(W_out[(size_t)(k + 0) * 64 + n]);
        o.y = f2bf(W_out[(size_t)(k + 1) * 64 + n]);
        o.z = f2bf(W_out[(size_t)(k + 2) * 64 + n]);
        o.w = f2bf(W_out[(size_t)(k + 3) * 64 + n]);
        *(ushort4*)(WoutT + (size_t)n * 256 + k) = o;
    } else {
        int i = (sb - 1200) * 256 + tid, st = 300 * 256;
        for (int k = i; k < NTN * 16; k += st) {            // NTN*64/4
            float4 v = ((const float4*)x_trans)[k];
            ushort4 o;
            o.x = f2bf(v.x); o.y = f2bf(v.y); o.z = f2bf(v.z); o.w = f2bf(v.w);
            ((ushort4*)xin0)[k] = o;
        }
        for (int k = i; k < NCN * 16; k += st) {
            float4 v = ((const float4*)x_cc)[k];
            ushort4 o;
            o.x = f2bf(v.x); o.y = f2bf(v.y); o.z = f2bf(v.z); o.w = f2bf(v.w);
            ((ushort4*)xin1)[k] = o;
        }
    }
}

// ------------------- mega prep 2: big weight transposes (reads Wf2) + edge histogram -------------------
// [0,1024): 4 transpose groups of 4x[256][256]; [1024,1806): hist for both relations.
__global__ __launch_bounds__(256) void prep2(
    const float* __restrict__ Wq, const float* __restrict__ Wf2, const float* __restrict__ Wa,
    u16* __restrict__ WqkvT, u16* __restrict__ WaT,
    const int* __restrict__ dst_c2t, unsigned* __restrict__ countsT,
    const int* __restrict__ dst_t2c, unsigned* __restrict__ countsC)
{
    const int sb = blockIdx.x, tid = threadIdx.x;
    if (sb < 1024) {
        const int g = sb >> 8;
        const float* in; u16* out; int inStride, outStride;
        switch (g) {
            case 0:  in = Wq;          out = WqkvT;          inStride = 65536;  outStride = 196608; break;
            case 1:  in = Wf2;         out = WqkvT + 65536;  inStride = 131072; outStride = 196608; break;
            case 2:  in = Wf2 + 65536; out = WqkvT + 131072; inStride = 131072; outStride = 196608; break;
            default: in = Wa;          out = WaT;            inStride = 65536;  outStride = 65536;  break;
        }
        int idx = (sb & 255) * 256 + tid;
        int mat = idx >> 14, rem = idx & 16383;
        int k4 = rem >> 8, n = rem & 255;
        int k = k4 * 4;
        const float* src = in + (size_t)mat * inStride;
        u16* dst = out + (size_t)mat * outStride;
        ushort4 o;
        o.x = f2bf(src[(size_t)(k + 0) * 256 + n]);
        o.y = f2bf(src[(size_t)(k + 1) * 256 + n]);
        o.z = f2bf(src[(size_t)(k + 2) * 256 + n]);
        o.w = f2bf(src[(size_t)(k + 3) * 256 + n]);
        *(ushort4*)(dst + (size_t)n * 256 + k) = o;
    } else {
        int e = (sb - 1024) * 256 + tid;
        if (e < NED) {
            atomicAdd(&countsT[dst_c2t[e]], 1u);
            atomicAdd(&countsC[dst_t2c[e]], 1u);
        }
    }
}

// ------------------------- MFMA GEMM (pair-merged; R11-proven core) -------------------------
// Two back-to-back GEMMs in one grid: blocks [0,nblk0) run set 0, rest set 1.
// Per set: C[M, NY*BN] = epi(A[M,K](bf16) @ WT^T(bf16) + bias).
// 64 x BN tile, BK=64, 4 waves, double-buffered LDS, counted vmcnt; 32KB LDS.
// EPI: 0=none, 1=relu, 2=skip-blend(bf16 out), 3=leakyrelu+row-L2-norm (f32 out,
// requires BN == total N == ldC so a block owns full rows).
template <int EPI, int BN, bool OBF>
__global__ __launch_bounds__(256) void gemm_mfma2(
    int nblk0,
    const u16* __restrict__ A0, const u16* __restrict__ W0, const float* __restrict__ b0,
    void* __restrict__ C0, int M0, int ldC0, int NY0,
    const u16* __restrict__ xr0, const float* __restrict__ sk0,
    const u16* __restrict__ A1, const u16* __restrict__ W1, const float* __restrict__ b1,
    void* __restrict__ C1, int M1, int ldC1, int NY1,
    const u16* __restrict__ xr1, const float* __restrict__ sk1,
    int K)
{
    constexpr int ASZ = 64 * 64;
    constexpr int BSZ = BN * 64;
    constexpr int NF = BN / 32;
    __shared__ u16 smem[2 * (ASZ + BSZ)];
    u16* As0 = smem;             u16* Bs0 = smem + ASZ;
    u16* As1 = smem + ASZ + BSZ; u16* Bs1 = As1 + ASZ;

    // bijective XCD swizzle (m204) over the merged grid
    const int nwg = gridDim.x;
    const int bid = blockIdx.x;
    const int q8 = nwg >> 3, r8 = nwg & 7;
    const int xcd = bid & 7, pos = bid >> 3;
    const int lbid = (xcd < r8) ? xcd * (q8 + 1) + pos
                                : r8 * (q8 + 1) + (xcd - r8) * q8 + pos;

    const u16* A; const u16* WT; const float* bias; void* Cv;
    int M, ldC, NY, sb; const u16* xres; const float* skipPtr;
    if (lbid < nblk0) {
        A = A0; WT = W0; bias = b0; Cv = C0; M = M0; ldC = ldC0; NY = NY0;
        xres = xr0; skipPtr = sk0; sb = lbid;
    } else {
        A = A1; WT = W1; bias = b1; Cv = C1; M = M1; ldC = ldC1; NY = NY1;
        xres = xr1; skipPtr = sk1; sb = lbid - nblk0;
    }
    const int bx = sb / NY, by = sb - bx * NY;
    const int m0 = bx * 64, n0 = by * BN;

    const int tid = threadIdx.x;
    const int wave = tid >> 6, lane = tid & 63;
    const int wm = (wave >> 1) * 32, wn = (wave & 1) * (BN / 2);
    f32x4 acc[2][NF];
#pragma unroll
    for (int i = 0; i < 2; ++i)
#pragma unroll
        for (int j = 0; j < NF; ++j) acc[i][j] = (f32x4){0.f, 0.f, 0.f, 0.f};

    const int sr = lane >> 3;
    const int sl = lane & 7;

    auto stage = [&](int k0, u16* Ad, u16* Bd) {
#pragma unroll
        for (int i = 0; i < 2; ++i) {
            int rb = wave * 16 + i * 8;
            int r = rb + sr;
            int gr = m0 + r; gr = gr < M ? gr : M - 1;
            const u16* gp = A + (size_t)gr * K + k0 + ((sl ^ sr) << 3);
            __builtin_amdgcn_global_load_lds(
                (const __attribute__((address_space(1))) void*)gp,
                (__attribute__((address_space(3))) void*)(Ad + rb * 64), 16, 0, 0);
        }
#pragma unroll
        for (int i = 0; i < NF; ++i) {
            int rb = wave * (BN / 4) + i * 8;
            int r = rb + sr;
            const u16* gp = WT + (size_t)(n0 + r) * K + k0 + ((sl ^ sr) << 3);
            __builtin_amdgcn_global_load_lds(
                (const __attribute__((address_space(1))) void*)gp,
                (__attribute__((address_space(3))) void*)(Bd + rb * 64), 16, 0, 0);
        }
    };

    auto compute = [&](const u16* Ab, const u16* Bb) {
#pragma unroll
        for (int kx = 0; kx < 2; ++kx) {
            bf16x8 af[2], bfr[NF];
#pragma unroll
            for (int mf = 0; mf < 2; ++mf) {
                int r = wm + mf * 16 + (lane & 15);
                int slot = (lane >> 4) + kx * 4;
                af[mf] = __builtin_bit_cast(bf16x8,
                    *(const u16x8*)(Ab + r * 64 + ((slot ^ (r & 7)) << 3)));
            }
#pragma unroll
            for (int nf = 0; nf < NF; ++nf) {
                int r = wn + nf * 16 + (lane & 15);
                int slot = (lane >> 4) + kx * 4;
                bfr[nf] = __builtin_bit_cast(bf16x8,
                    *(const u16x8*)(Bb + r * 64 + ((slot ^ (r & 7)) << 3)));
            }
#pragma unroll
            for (int mf = 0; mf < 2; ++mf)
#pragma unroll
                for (int nf = 0; nf < NF; ++nf)
                    acc[mf][nf] = __builtin_amdgcn_mfma_f32_16x16x32_bf16(
                        af[mf], bfr[nf], acc[mf][nf], 0, 0, 0);
        }
    };

    const int nt = K >> 6;
    stage(0, As0, Bs0);
    for (int t = 0; t < nt; ++t) {
        const bool pb = t & 1;
        if (t + 1 < nt) {
            stage((t + 1) << 6, pb ? As0 : As1, pb ? Bs0 : Bs1);
            __builtin_amdgcn_sched_barrier(0);
            if constexpr (BN == 128) asm volatile("s_waitcnt vmcnt(6)" ::: "memory");
            else                     asm volatile("s_waitcnt vmcnt(4)" ::: "memory");
        } else {
            asm volatile("s_waitcnt vmcnt(0)" ::: "memory");
        }
        __builtin_amdgcn_s_barrier();
        __builtin_amdgcn_sched_barrier(0);
        compute(pb ? As1 : As0, pb ? Bs1 : Bs0);
        __builtin_amdgcn_sched_barrier(0);
        __builtin_amdgcn_s_barrier();
        __builtin_amdgcn_sched_barrier(0);   // fence: next stage must not hoist above
    }

    float beta = 0.f;
    if (EPI == 2) beta = 1.f / (1.f + expf(-skipPtr[0]));

    if constexpr (EPI == 3) {
        // fused leakyrelu + row-L2-normalize + f32 store. Block owns full rows (BN == ldC).
        constexpr int CLDF = BN + 4;
        float* Cf = (float*)smem;   // 64 * 68 * 4 = 17.4 KB <= 32 KB
#pragma unroll
        for (int nf = 0; nf < NF; ++nf) {
            int col = wn + nf * 16 + (lane & 15);
            float bs = bias[n0 + col];
#pragma unroll
            for (int mf = 0; mf < 2; ++mf) {
#pragma unroll
                for (int j = 0; j < 4; ++j) {
                    int row = wm + mf * 16 + (lane >> 4) * 4 + j;
                    float c = acc[mf][nf][j] + bs;
                    c = (c > 0.f) ? c : 0.2f * c;
                    Cf[row * CLDF + col] = c;
                }
            }
        }
        __syncthreads();
        // 4 threads per row; quad shfl reduce of sum-of-squares; coalesced f32 writes
        int row = tid >> 2, q = tid & 3;
        float4 v[4];
        float ss = 0.f;
#pragma unroll
        for (int i = 0; i < 4; ++i) {
            v[i] = *(const float4*)(Cf + row * CLDF + q * 16 + i * 4);
            ss += v[i].x * v[i].x + v[i].y * v[i].y + v[i].z * v[i].z + v[i].w * v[i].w;
        }
        ss += __shfl_xor(ss, 1);
        ss += __shfl_xor(ss, 2);
        float nrm = sqrtf(ss);
        float inv = 1.f / fmaxf(nrm, 1e-12f);
        int grow = m0 + row;
        if (grow < M) {
            float* dst = (float*)Cv + (size_t)grow * ldC + q * 16;
#pragma unroll
            for (int i = 0; i < 4; ++i) {
                float4 o;
                o.x = v[i].x * inv; o.y = v[i].y * inv;
                o.z = v[i].z * inv; o.w = v[i].w * inv;
                *(float4*)(dst + i * 4) = o;
            }
        }
    } else if constexpr (OBF) {
        constexpr int CLD = BN + 8;
        u16* Ct = smem;
#pragma unroll
        for (int nf = 0; nf < NF; ++nf) {
            int col = wn + nf * 16 + (lane & 15);
            int gcol = n0 + col;
            float bs = bias[gcol];
#pragma unroll
            for (int mf = 0; mf < 2; ++mf) {
#pragma unroll
                for (int j = 0; j < 4; ++j) {
                    int row = wm + mf * 16 + (lane >> 4) * 4 + j;
                    int grow = m0 + row;
                    int gr2 = grow < M ? grow : 0;
                    float c = acc[mf][nf][j] + bs;
                    if (EPI == 1) c = fmaxf(c, 0.f);
                    if (EPI == 2) c = beta * c + (1.f - beta) * bf2f(xres[(size_t)gr2 * ldC + gcol]);
                    Ct[row * CLD + col] = f2bf(c);
                }
            }
        }
        __syncthreads();   // full lgkm drain + fence: cross-wave LDS handoff
        int row = tid >> 2, c0 = (tid & 3) * (BN / 4);
        int grow = m0 + row;
        if (grow < M) {
            u16* dst = (u16*)Cv + (size_t)grow * ldC + n0 + c0;
            const u16* src = Ct + row * CLD + c0;
#pragma unroll
            for (int i = 0; i < BN / 32; ++i)
                *(u16x8*)(dst + i * 8) = *(const u16x8*)(src + i * 8);
        }
    } else {
#pragma unroll
        for (int nf = 0; nf < NF; ++nf) {
            int gcol = n0 + wn + nf * 16 + (lane & 15);
            float bs = bias[gcol];
#pragma unroll
            for (int mf = 0; mf < 2; ++mf) {
#pragma unroll
                for (int j = 0; j < 4; ++j) {
                    int grow = m0 + wm + mf * 16 + (lane >> 4) * 4 + j;
                    if (grow >= M) continue;
                    float c = acc[mf][nf][j] + bs;
                    if (EPI == 1) c = fmaxf(c, 0.f);
                    ((float*)Cv)[(size_t)grow * ldC + gcol] = c;
                }
            }
        }
    }
}

// ------------------------- CSR scan chain (both relations per launch) -------------------------
__global__ __launch_bounds__(256) void scan_blocks2(
    const unsigned* __restrict__ c0, unsigned* __restrict__ p0, unsigned* __restrict__ bs0, int N0,
    const unsigned* __restrict__ c1, unsigned* __restrict__ p1, unsigned* __restrict__ bs1, int N1)
{
    const unsigned* counts = blockIdx.y ? c1 : c0;
    unsigned* pref = blockIdx.y ? p1 : p0;
    unsigned* bsum = blockIdx.y ? bs1 : bs0;
    int N = blockIdx.y ? N1 : N0;
    if ((int)blockIdx.x * 256 >= N) return;   // block-uniform early-out
    __shared__ unsigned tmp[256];
    int i = blockIdx.x * 256 + threadIdx.x;
    unsigned v = (i < N) ? counts[i] : 0u;
    tmp[threadIdx.x] = v;
    __syncthreads();
    for (int off = 1; off < 256; off <<= 1) {
        unsigned t = (threadIdx.x >= off) ? tmp[threadIdx.x - off] : 0u;
        __syncthreads();
        tmp[threadIdx.x] += t;
        __syncthreads();
    }
    if (i < N) pref[i] = tmp[threadIdx.x] - v;  // exclusive
    if (threadIdx.x == 255) bsum[blockIdx.x] = tmp[255];
}

__global__ __launch_bounds__(256) void scan_top2(
    unsigned* __restrict__ bs0, int NB0, unsigned* __restrict__ bs1, int NB1)
{
    unsigned* bsum = blockIdx.x ? bs1 : bs0;
    int NB = blockIdx.x ? NB1 : NB0;
    __shared__ unsigned tmp[256];
    unsigned v = ((int)threadIdx.x < NB) ? bsum[threadIdx.x] : 0u;
    tmp[threadIdx.x] = v;
    __syncthreads();
    for (int off = 1; off < 256; off <<= 1) {
        unsigned t = (threadIdx.x >= off) ? tmp[threadIdx.x - off] : 0u;
        __syncthreads();
        tmp[threadIdx.x] += t;
        __syncthreads();
    }
    if ((int)threadIdx.x < NB) bsum[threadIdx.x] = tmp[threadIdx.x] - v;  // exclusive
}

// packs rowstart|deg into one u64 per node (single load in edge kernel)
__global__ void scan_add2(
    const unsigned* __restrict__ p0, const unsigned* __restrict__ bs0,
    const unsigned* __restrict__ c0, unsigned* __restrict__ cur0, u64* __restrict__ ri0, int N0,
    const unsigned* __restrict__ p1, const unsigned* __restrict__ bs1,
    const unsigned* __restrict__ c1, unsigned* __restrict__ cur1, u64* __restrict__ ri1, int N1)
{
    const unsigned* pref = blockIdx.y ? p1 : p0;
    const unsigned* bsum = blockIdx.y ? bs1 : bs0;
    const unsigned* counts = blockIdx.y ? c1 : c0;
    unsigned* cursor = blockIdx.y ? cur1 : cur0;
    u64* rowinfo = blockIdx.y ? ri1 : ri0;
    int N = blockIdx.y ? N1 : N0;
    int i = blockIdx.x * 256 + threadIdx.x;
    if (i < N) {
        unsigned s = pref[i] + bsum[blockIdx.x];
        cursor[i] = s;
        rowinfo[i] = (u64)s | ((u64)counts[i] << 32);
    }
}

// stores PRE-MULTIPLIED row offset (src*768, u16 units).
__global__ void place2(const int* __restrict__ d0, const int* __restrict__ s0,
                       unsigned* __restrict__ cur0, unsigned* __restrict__ o0,
                       const int* __restrict__ d1, const int* __restrict__ s1,
                       unsigned* __restrict__ cur1, unsigned* __restrict__ o1, int E) {
    int e = blockIdx.x * blockDim.x + threadIdx.x;
    if (e < E) {
        unsigned p = atomicAdd(&cur0[d0[e]], 1u);
        o0[p] = (unsigned)s0[e] * 768u;
        unsigned q = atomicAdd(&cur1[d1[e]], 1u);
        o1[q] = (unsigned)s1[e] * 768u;
    }
}

// ------------------------- fused edge gather (2 nodes per wave) -------------------------
// Each 32-lane HALF owns ONE dst node (32 lanes x 16B = full 256-wide row):
// no cross-half merge; q-prep/softmax-finish/gelu/store serve 2 nodes per
// wave instruction. Online softmax w/ defer-max ballot fast path.
#define TBLK8 ((NTN + 7) / 8)
__global__ __launch_bounds__(256) void edge_gather2(
    const u16* __restrict__ qkvT, const u16* __restrict__ qkvC,
    const u64* __restrict__ riT, const unsigned* __restrict__ srcT,
    const u64* __restrict__ riC, const unsigned* __restrict__ srcC,
    u16* __restrict__ aggT, u16* __restrict__ aggC)
{
    const int b = blockIdx.x;
    const bool isT = b < TBLK8;
    const int lane = threadIdx.x & 63;
    const int lq = lane & 31;
    const int n = (((isT ? b : b - TBLK8) << 2) + (int)(threadIdx.x >> 6)) * 2 + (lane >> 5);

    const u16* qkv_d = isT ? qkvT : qkvC;
    const u16* qkv_s = isT ? qkvC : qkvT;
    const u64* ri = isT ? riT : riC;
    const unsigned* srcarr = isT ? srcT : srcC;
    u16* agg = isT ? aggT : aggC;

    const u64 rinfo = ri[n];
    const unsigned start = (unsigned)rinfo;
    const unsigned deg = (unsigned)(rinfo >> 32);
    u16* outp = &agg[(size_t)n * 256 + lq * 8];

    if (deg == 0) {
        *(u16x8*)outp = (u16x8){0, 0, 0, 0, 0, 0, 0, 0};
        return;
    }

    u16x8 qv = *(const u16x8*)&qkv_d[(size_t)n * 768 + lq * 8];
    float qf[8];
#pragma unroll
    for (int i = 0; i < 8; ++i) qf[i] = bf2f(qv[i]);

    const u16* kvb = qkv_s + 256 + lq * 8;   // k section base (lane folded); v at +256
    float m = -INFINITY, s = 0.f;
    float acc[8] = {0.f, 0.f, 0.f, 0.f, 0.f, 0.f, 0.f, 0.f};

    unsigned off = srcarr[start];
    u16x8 kr = *(const u16x8*)(kvb + off);
    u16x8 vr = *(const u16x8*)(kvb + off + 256);
    for (unsigned j = 0;;) {
        const bool more = (j + 1 < deg);
        u16x8 kr_n, vr_n;
        if (more) {
            unsigned off2 = srcarr[start + j + 1];
            kr_n = *(const u16x8*)(kvb + off2);
            vr_n = *(const u16x8*)(kvb + off2 + 256);
        }
        float kf[8];
#pragma unroll
        for (int i = 0; i < 8; ++i) kf[i] = bf2f(kr[i]);
        float p = qf[0] * kf[0] + qf[1] * kf[1] + qf[2] * kf[2] + qf[3] * kf[3]
                + qf[4] * kf[4] + qf[5] * kf[5] + qf[6] * kf[6] + qf[7] * kf[7];
        p += __shfl_xor(p, 1);
        p += __shfl_xor(p, 2);          // quad = the 4 lanes of this head (within half)
        float vf[8];
#pragma unroll
        for (int i = 0; i < 8; ++i) vf[i] = bf2f(vr[i]);
        if (__ballot(p > m) == 0ull) {
            float wv = __expf(p - m);
            s += wv;
#pragma unroll
            for (int i = 0; i < 8; ++i) acc[i] += wv * vf[i];
        } else {
            float mn = fmaxf(m, p);
            float sc = __expf(m - mn);  // 0 on first iteration (m = -inf)
            float wv = __expf(p - mn);
            s = s * sc + wv;
#pragma unroll
            for (int i = 0; i < 8; ++i) acc[i] = acc[i] * sc + wv * vf[i];
            m = mn;
        }
        if (!more) break;
        kr = kr_n; vr = vr_n; ++j;
    }

    float inv = 1.f / (s + 1e-16f);
    u16x8 ov;
#pragma unroll
    for (int i = 0; i < 8; ++i) {
        float x = acc[i] * inv;
        // gelu(x) ~= 0.5x(1+tanh(0.79788456(x+0.044715x^3))), tanh via expf
        float y2 = 1.5957691216f * x + 0.0713548163f * x * x * x;  // 2*y
        float e = __expf(y2);
        float t = 1.f - 2.f / (e + 1.f);
        ov[i] = f2bf(0.5f * x * (1.f + t));
    }
    *(u16x8*)outp = ov;
}

// ------------------------- launch -------------------------
extern "C" void kernel_launch(void* const* d_in, const int* in_sizes, int n_in,
                              void* d_out, int out_size, void* d_ws, size_t ws_size,
                              hipStream_t stream)
{
    const float* x_trans = (const float*)d_in[0];
    const float* x_cc    = (const float*)d_in[1];
    const int* src_c2t   = (const int*)d_in[2];
    const int* dst_c2t   = (const int*)d_in[3];
    const int* src_t2c   = (const int*)d_in[4];
    const int* dst_t2c   = (const int*)d_in[5];
    const float* W_in = (const float*)d_in[6];
    const float* b_in = (const float*)d_in[7];
    const float* Wk   = (const float*)d_in[8];
    const float* bk   = (const float*)d_in[9];
    const float* Wq   = (const float*)d_in[10];
    const float* bq   = (const float*)d_in[11];
    const float* Wv   = (const float*)d_in[12];
    const float* bv   = (const float*)d_in[13];
    const float* Wa   = (const float*)d_in[14];
    const float* ba   = (const float*)d_in[15];
    const float* a_rel = (const float*)d_in[16];
    const float* m_rel = (const float*)d_in[17];
    const float* p_rel = (const float*)d_in[18];
    const float* skip  = (const float*)d_in[19];
    const float* W_out = (const float*)d_in[20];
    const float* b_out = (const float*)d_in[21];

    // ---------- workspace layout (~251 MB) ----------
    char* w = (char*)d_ws;
    auto alloc = [&](size_t bytes) { char* p = w; w += (bytes + 255) & ~(size_t)255; return p; };
    u16* xs0  = (u16*)alloc((size_t)NTN * 256 * 2);
    u16* xs1  = (u16*)alloc((size_t)NCN * 256 * 2);
    u16* xin0 = (u16*)alloc((size_t)NTN * 64 * 2);
    u16* xin1 = (u16*)alloc((size_t)NCN * 64 * 2);
    u16* qkv0 = (u16*)alloc((size_t)NTN * 768 * 2);   // 92.2 MB
    u16* qkv1 = (u16*)alloc((size_t)NCN * 768 * 2);   // 46.1 MB
    u16* agg0 = (u16*)alloc((size_t)NTN * 256 * 2);
    u16* agg1 = (u16*)alloc((size_t)NCN * 256 * 2);
    u16* WinT = (u16*)alloc((size_t)2 * 16384 * 2);
    u16* WqkvT= (u16*)alloc((size_t)4 * 196608 * 2);  // [768][256] per lt
    u16* WaT  = (u16*)alloc((size_t)4 * 65536 * 2);
    u16* WoutT= (u16*)alloc((size_t)16384 * 2);
    float* Wf2 = (float*)alloc((size_t)4 * 131072 * 4); // [lt][kf|vf] f32 staging
    float* bqkv = (float*)alloc((size_t)4 * 768 * 4);
    unsigned* countsT   = (unsigned*)alloc((size_t)NTN * 4);
    unsigned* prefT     = (unsigned*)alloc((size_t)NTN * 4);
    unsigned* cursorT   = (unsigned*)alloc((size_t)NTN * 4);
    u64* rowinfoT       = (u64*)alloc((size_t)NTN * 8);
    unsigned* srcAT     = (unsigned*)alloc((size_t)NED * 4);
    unsigned* countsC   = (unsigned*)alloc((size_t)NCN * 4);
    unsigned* prefC     = (unsigned*)alloc((size_t)NCN * 4);
    unsigned* cursorC   = (unsigned*)alloc((size_t)NCN * 4);
    u64* rowinfoC       = (u64*)alloc((size_t)NCN * 8);
    unsigned* srcAC     = (unsigned*)alloc((size_t)NED * 4);
    unsigned* bsum      = (unsigned*)alloc((size_t)2 * 256 * 4);
    (void)ws_size; (void)in_sizes; (void)n_in; (void)out_size;

    // ---------- mega prep (2 launches) + CSR scan chain ----------
    prep1<<<1500, 256, 0, stream>>>(countsT, countsC, Wk, bk, Wv, bv,
                                    a_rel, m_rel, p_rel, Wf2, bqkv, bq,
                                    W_in, WinT, W_out, WoutT,
                                    x_trans, xin0, x_cc, xin1);
    prep2<<<1024 + (NED + 255) / 256, 256, 0, stream>>>(Wq, Wf2, Wa, WqkvT, WaT,
                                                        dst_c2t, countsT, dst_t2c, countsC);
    {
        const int NBt = (NTN + 255) / 256, NBc = (NCN + 255) / 256;
        scan_blocks2<<<dim3(NBt, 2), 256, 0, stream>>>(countsT, prefT, bsum, NTN,
                                                       countsC, prefC, bsum + 256, NCN);
        scan_top2<<<2, 256, 0, stream>>>(bsum, NBt, bsum + 256, NBc);
        scan_add2<<<dim3(NBt, 2), 256, 0, stream>>>(
            prefT, bsum, countsT, cursorT, rowinfoT, NTN,
            prefC, bsum + 256, countsC, cursorC, rowinfoC, NCN);
        place2<<<(NED + 255) / 256, 256, 0, stream>>>(dst_c2t, src_c2t, cursorT, srcAT,
                                                      dst_t2c, src_t2c, cursorC, srcAC, NED);
    }

    const int GT = (NTN + 63) / 64, GC = (NCN + 63) / 64;   // 938 / 469

    // ---------- input projections + relu (pair-merged) ----------
    gemm_mfma2<1, 64, true><<<GT * 4 + GC * 4, 256, 0, stream>>>(
        GT * 4,
        xin0, WinT, b_in, xs0, NTN, 256, 4, nullptr, nullptr,
        xin1, WinT + 16384, b_in + 256, xs1, NCN, 256, 4, nullptr, nullptr,
        64);

    for (int l = 0; l < 2; ++l) {
        size_t lt0 = (size_t)(l * 2 + 0), lt1 = (size_t)(l * 2 + 1);

        // fused q|k|v projections, both node types in one launch
        gemm_mfma2<0, 64, true><<<GT * 12 + GC * 12, 256, 0, stream>>>(
            GT * 12,
            xs0, WqkvT + lt0 * 196608, bqkv + lt0 * 768, qkv0, NTN, 768, 12, nullptr, nullptr,
            xs1, WqkvT + lt1 * 196608, bqkv + lt1 * 768, qkv1, NCN, 768, 12, nullptr, nullptr,
            256);

        // both edge phases in one launch, 2 nodes per wave
        edge_gather2<<<TBLK8 + (NCN + 7) / 8, 256, 0, stream>>>(
            qkv0, qkv1,
            rowinfoT, srcAT,
            rowinfoC, srcAC,
            agg0, agg1);

        // skip-blend output transforms, both node types in one launch
        gemm_mfma2<2, 64, true><<<GT * 4 + GC * 4, 256, 0, stream>>>(
            GT * 4,
            agg0, WaT + lt0 * 65536, ba + lt0 * 256, xs0, NTN, 256, 4, xs0, skip + l * 2 + 0,
            agg1, WaT + lt1 * 65536, ba + lt1 * 256, xs1, NCN, 256, 4, xs1, skip + l * 2 + 1,
            256);
    }

    // ---------- final projection + leakyrelu + row L2 normalize (fused) ----------
    {
        float* y = (float*)d_out;
        gemm_mfma2<3, 64, false><<<GT, 256, 0, stream>>>(
            GT,
            xs0, WoutT, b_out, y, NTN, 64, 1, nullptr, nullptr,
            xs0, WoutT, b_out, y, NTN, 64, 1, nullptr, nullptr,
            256);
    }
}